// Round 13
// baseline (140.689 us; speedup 1.0000x reference)
//
#include <hip/hip_runtime.h>
#include <hip/hip_bf16.h>

#define DEVFN __device__ __forceinline__

typedef __attribute__((ext_vector_type(8))) short bf16x8;   // 8 bf16 = 4 VGPR
typedef __attribute__((ext_vector_type(4))) float f32x4;
typedef __attribute__((ext_vector_type(16))) float f32x16;

constexpr int Bc = 2, Sc = 2048, Dc = 1024, Hc = 16, HDc = 64;
constexpr float SCALEc = 0.125f;  // HD^-0.5
constexpr float LOG2E  = 1.44269504088896340736f;

DEVFN unsigned short f2bf(float f) {  // RNE fp32 -> bf16
    union { float f; unsigned int u; } x; x.f = f;
    return (unsigned short)((x.u + 0x7fffu + ((x.u >> 16) & 1u)) >> 16);
}

DEVFN f32x4 mfma16(bf16x8 a, bf16x8 b, f32x4 c) {
    return __builtin_amdgcn_mfma_f32_16x16x32_bf16(a, b, c, 0, 0, 0);
}
DEVFN f32x16 mfma32(bf16x8 a, bf16x8 b, f32x16 c) {
    return __builtin_amdgcn_mfma_f32_32x32x16_bf16(a, b, c, 0, 0, 0);
}

DEVFN void gload16(const void* g, void* l) {  // async global->LDS, dest = base + lane*16
    __builtin_amdgcn_global_load_lds((const __attribute__((address_space(1))) void*)g,
                                     (__attribute__((address_space(3))) void*)l, 16, 0, 0);
}

// ---- weights fp32 -> bf16 (4 x 1M elems) ----
__global__ __launch_bounds__(256) void cvt_w(
    const float* __restrict__ wq, const float* __restrict__ wk,
    const float* __restrict__ wv, const float* __restrict__ wo,
    unsigned short* __restrict__ wqb, unsigned short* __restrict__ wkb,
    unsigned short* __restrict__ wvb, unsigned short* __restrict__ wob)
{
    const unsigned t = blockIdx.x * 256 + threadIdx.x;   // 524288 threads
    const unsigned which = t >> 17, local = t & ((1u << 17) - 1);
    const float* s = which == 0 ? wq : which == 1 ? wk : which == 2 ? wv : wo;
    unsigned short* d = which == 0 ? wqb : which == 1 ? wkb : which == 2 ? wvb : wob;
    const size_t off = (size_t)local * 8;
    float4 v0 = *(const float4*)(s + off);
    float4 v1 = *(const float4*)(s + off + 4);
    unsigned short t8[8] = {f2bf(v0.x), f2bf(v0.y), f2bf(v0.z), f2bf(v0.w),
                            f2bf(v1.x), f2bf(v1.y), f2bf(v1.z), f2bf(v1.w)};
    *(uint4*)(d + off) = *(const uint4*)t8;
}

// ---- fused QKV projection, 256x256 tile, BK=64, 8 waves (2Mx4N), 128KB LDS dbuf.
// A = fp32 reg-staged (float4 loads issued at step top, cvt_pk after MFMA -> swizzled
// ds_write); B = bf16 via global_load_lds (pre-swizzled source). One barrier per step;
// the 64-MFMA block covers load latency (implicit vmcnt before cvt = pipeline heartbeat).
// swz(r) = (r&7)^(((r>>3)&1)<<2) on 16B slots: uniform bank spread on all b128 ops.
// Q pre-scaled by SCALE*log2e. g<2: out [B,H,S,HD]; g==2: out [B,H,HD,S], k-bits 2<->3
// swapped per 16-group (attention PV fragment permutation carried in memory).
__global__ __launch_bounds__(512, 2) void qkv_gemm(
    const float* __restrict__ Aq, const float* __restrict__ Ak, const float* __restrict__ Av,
    const unsigned short* __restrict__ Wqb, const unsigned short* __restrict__ Wkb,
    const unsigned short* __restrict__ Wvb,
    const float* __restrict__ bqp, const float* __restrict__ bkp, const float* __restrict__ bvp,
    unsigned short* __restrict__ Qo, unsigned short* __restrict__ Ko, unsigned short* __restrict__ Vto)
{
    __shared__ short As[2 * 16384];   // [buf][256 rows][64 k], 32KB per buf
    __shared__ short Bs[2 * 16384];

    // XCD-chunked decode: logical id ordered g*64 + tm*4 + tn so the 4 blocks sharing
    // an A-panel (tn=0..3) are consecutive -> same XCD L2. 192 % 8 == 0 (bijective).
    const int lgid = (blockIdx.x & 7) * 24 + (blockIdx.x >> 3);
    const int g = lgid >> 6;
    const int rr = lgid & 63;
    const int tm = rr >> 2, tn = rr & 3;

    const float* A = g == 0 ? Aq : g == 1 ? Ak : Av;
    const unsigned short* Bw = g == 0 ? Wqb : g == 1 ? Wkb : Wvb;
    const float* bias = g == 0 ? bqp : g == 1 ? bkp : bvp;
    const float scale = g == 0 ? SCALEc * LOG2E : 1.0f;

    const int tid = threadIdx.x, lane = tid & 63, w = tid >> 6;   // 8 waves
    const int lr = lane & 15, lgq = lane >> 4;
    const int wm = (w >> 2) * 128, wn = (w & 3) * 64;   // per-wave 128x64 output

    // ---- A staging coords: thread -> (row ra, k-half kh); 8 float4 = 32 fp32 ----
    const int ra = tid >> 1, kh = tid & 1;
    const int swzra = (ra & 7) ^ (((ra >> 3) & 1) << 2);
    const float* Ap = A + (size_t)(tm * 256 + ra) * 1024 + kh * 32;
    const int aw0 = ra * 64 + (((kh * 4 + 0) ^ swzra) * 8);
    const int aw1 = ra * 64 + (((kh * 4 + 1) ^ swzra) * 8);
    const int aw2 = ra * 64 + (((kh * 4 + 2) ^ swzra) * 8);
    const int aw3 = ra * 64 + (((kh * 4 + 3) ^ swzra) * 8);

    // ---- B staging: wave w stages rows w*32..+31; 4 glds x (8 rows x 128B) ----
    const int l3 = lane >> 3, l7 = lane & 7;
    const unsigned short* Bp[4];
    #pragma unroll
    for (int i = 0; i < 4; i++) {
        const int rb = w * 32 + i * 8 + l3;
        const int swzrb = (rb & 7) ^ (((rb >> 3) & 1) << 2);
        Bp[i] = Bw + (size_t)(tn * 256 + rb) * 1024 + ((l7 ^ swzrb) * 8);
    }
    const int bdst = (w * 32) * 64;   // wave-uniform; + i*512 per gld; HW adds lane*16B

    const int swzL = (lr & 7) ^ (((lr >> 3) & 1) << 2);   // read-side, const per lane

    f32x4 acc[8][4] = {};
    float4 fA0, fA1, fA2, fA3, fA4, fA5, fA6, fA7;

#define LOAD_A(KO)                                                               \
    fA0 = *(const float4*)(Ap + (KO));      fA1 = *(const float4*)(Ap + (KO) + 4);  \
    fA2 = *(const float4*)(Ap + (KO) + 8);  fA3 = *(const float4*)(Ap + (KO) + 12); \
    fA4 = *(const float4*)(Ap + (KO) + 16); fA5 = *(const float4*)(Ap + (KO) + 20); \
    fA6 = *(const float4*)(Ap + (KO) + 24); fA7 = *(const float4*)(Ap + (KO) + 28);

#define CVT_A(BUFOFS)                                                            \
    {                                                                            \
        unsigned int q0, q1, q2, q3;                                             \
        asm("v_cvt_pk_bf16_f32 %0,%1,%2" : "=v"(q0) : "v"(fA0.x), "v"(fA0.y));   \
        asm("v_cvt_pk_bf16_f32 %0,%1,%2" : "=v"(q1) : "v"(fA0.z), "v"(fA0.w));   \
        asm("v_cvt_pk_bf16_f32 %0,%1,%2" : "=v"(q2) : "v"(fA1.x), "v"(fA1.y));   \
        asm("v_cvt_pk_bf16_f32 %0,%1,%2" : "=v"(q3) : "v"(fA1.z), "v"(fA1.w));   \
        *(uint4*)&As[(BUFOFS) + aw0] = (uint4){q0, q1, q2, q3};                  \
        asm("v_cvt_pk_bf16_f32 %0,%1,%2" : "=v"(q0) : "v"(fA2.x), "v"(fA2.y));   \
        asm("v_cvt_pk_bf16_f32 %0,%1,%2" : "=v"(q1) : "v"(fA2.z), "v"(fA2.w));   \
        asm("v_cvt_pk_bf16_f32 %0,%1,%2" : "=v"(q2) : "v"(fA3.x), "v"(fA3.y));   \
        asm("v_cvt_pk_bf16_f32 %0,%1,%2" : "=v"(q3) : "v"(fA3.z), "v"(fA3.w));   \
        *(uint4*)&As[(BUFOFS) + aw1] = (uint4){q0, q1, q2, q3};                  \
        asm("v_cvt_pk_bf16_f32 %0,%1,%2" : "=v"(q0) : "v"(fA4.x), "v"(fA4.y));   \
        asm("v_cvt_pk_bf16_f32 %0,%1,%2" : "=v"(q1) : "v"(fA4.z), "v"(fA4.w));   \
        asm("v_cvt_pk_bf16_f32 %0,%1,%2" : "=v"(q2) : "v"(fA5.x), "v"(fA5.y));   \
        asm("v_cvt_pk_bf16_f32 %0,%1,%2" : "=v"(q3) : "v"(fA5.z), "v"(fA5.w));   \
        *(uint4*)&As[(BUFOFS) + aw2] = (uint4){q0, q1, q2, q3};                  \
        asm("v_cvt_pk_bf16_f32 %0,%1,%2" : "=v"(q0) : "v"(fA6.x), "v"(fA6.y));   \
        asm("v_cvt_pk_bf16_f32 %0,%1,%2" : "=v"(q1) : "v"(fA6.z), "v"(fA6.w));   \
        asm("v_cvt_pk_bf16_f32 %0,%1,%2" : "=v"(q2) : "v"(fA7.x), "v"(fA7.y));   \
        asm("v_cvt_pk_bf16_f32 %0,%1,%2" : "=v"(q3) : "v"(fA7.z), "v"(fA7.w));   \
        *(uint4*)&As[(BUFOFS) + aw3] = (uint4){q0, q1, q2, q3};                  \
    }

    // ---- prologue: stage tile 0 into buf 0 ----
    gload16(Bp[0], &Bs[bdst + 0]);
    gload16(Bp[1], &Bs[bdst + 512]);
    gload16(Bp[2], &Bs[bdst + 1024]);
    gload16(Bp[3], &Bs[bdst + 1536]);
    LOAD_A(0)
    CVT_A(0)                                   // implicit vmcnt wait drains B too
    asm volatile("s_waitcnt vmcnt(0) lgkmcnt(0)" ::: "memory");
    __builtin_amdgcn_s_barrier();

    for (int t = 0; t < 16; ++t) {
        const int Pofs = (t & 1) * 16384;
        const int Nofs = Pofs ^ 16384;
        if (t < 15) {                           // stage tile t+1
            const int ko = (t + 1) * 64;
            gload16(Bp[0] + ko, &Bs[Nofs + bdst + 0]);
            gload16(Bp[1] + ko, &Bs[Nofs + bdst + 512]);
            gload16(Bp[2] + ko, &Bs[Nofs + bdst + 1024]);
            gload16(Bp[3] + ko, &Bs[Nofs + bdst + 1536]);
            LOAD_A(ko)
        }

        __builtin_amdgcn_s_setprio(1);
        #pragma unroll
        for (int kh2 = 0; kh2 < 2; kh2++) {     // two 32-k halves of the 64-k tile
            const int sA = ((lgq + kh2 * 4) ^ swzL) * 8;
            bf16x8 af[8], bf[4];
            #pragma unroll
            for (int m = 0; m < 8; m++)
                af[m] = *(const bf16x8*)&As[Pofs + (wm + m * 16 + lr) * 64 + sA];
            #pragma unroll
            for (int n = 0; n < 4; n++)
                bf[n] = *(const bf16x8*)&Bs[Pofs + (wn + n * 16 + lr) * 64 + sA];
            #pragma unroll
            for (int m = 0; m < 8; m++)
                #pragma unroll
                for (int n = 0; n < 4; n++)
                    acc[m][n] = mfma16(af[m], bf[n], acc[m][n]);
        }
        __builtin_amdgcn_s_setprio(0);

        if (t < 15) { CVT_A(Nofs) }             // implicit vmcnt: covered by 64 MFMA
        asm volatile("s_waitcnt lgkmcnt(0)" ::: "memory");
        __builtin_amdgcn_sched_barrier(0);
        __builtin_amdgcn_s_barrier();
    }
#undef LOAD_A
#undef CVT_A

    if (g < 2) {
        unsigned short* Y = g == 0 ? Qo : Ko;
        #pragma unroll
        for (int n = 0; n < 4; n++) {
            const int col = tn * 256 + wn + n * 16 + lr;
            const float bv = bias[col];
            const int hh = col >> 6, hd = col & 63;
            #pragma unroll
            for (int m = 0; m < 8; m++) {
                const int row0 = tm * 256 + wm + m * 16 + lgq * 4;
                const int b_ = row0 >> 11, sQ = row0 & 2047;
                #pragma unroll
                for (int r = 0; r < 4; r++) {
                    const float val = (acc[m][n][r] + bv) * scale;
                    Y[(((size_t)(b_ * Hc + hh)) * Sc + (sQ + r)) * HDc + hd] = f2bf(val);
                }
            }
        }
    } else {
        #pragma unroll
        for (int n = 0; n < 4; n++) {
            const int col = tn * 256 + wn + n * 16 + lr;
            const float bv = bias[col];
            const int hh = col >> 6, hd = col & 63;
            #pragma unroll
            for (int m = 0; m < 8; m++) {
                const int row0 = tm * 256 + wm + m * 16 + lgq * 4;
                const int b_ = row0 >> 11, sQ = row0 & 2047;
                const int sQp = (sQ & ~12) | ((sQ & 4) << 1) | ((sQ & 8) >> 1);  // k bits 2<->3
                unsigned long long pk = 0;
                #pragma unroll
                for (int r = 0; r < 4; r++)
                    pk |= (unsigned long long)f2bf(acc[m][n][r] + bv) << (16 * r);
                *(unsigned long long*)&Vto[(((size_t)(b_ * Hc + hh)) * HDc + hd) * Sc + sQp] = pk;
            }
        }
    }
}

// ---- output projection: R12 dbuf version (bf16 A from attn, bf16 Wo) ----
__global__ __launch_bounds__(256) void out_gemm(
    const unsigned short* __restrict__ Ab, const unsigned short* __restrict__ Bw,
    const float* __restrict__ bias, float* __restrict__ Y)
{
    __shared__ short As[2][4096];
    __shared__ short Bs[2][4096];
    const int tid = threadIdx.x, lane = tid & 63, w = tid >> 6;
    const int lr = lane & 15, lg = lane >> 4;
    const int tm = blockIdx.x & 31, tn = blockIdx.x >> 5;
    const int wm = (w >> 1) * 64, wn = (w & 1) * 64;

    const int c0 = 2 * w, c1 = 2 * w + 1;
    const int r0 = c0 * 16 + (lane >> 2), r1 = c1 * 16 + (lane >> 2);
    const int sl0 = ((lane & 3) ^ ((r0 >> 1) & 3)) * 8, sl1 = ((lane & 3) ^ ((r1 >> 1) & 3)) * 8;
    const unsigned short* Ap0 = Ab + (size_t)(tm * 128 + r0) * 1024 + sl0;
    const unsigned short* Ap1 = Ab + (size_t)(tm * 128 + r1) * 1024 + sl1;
    const unsigned short* Bp0 = Bw + (size_t)(tn * 128 + r0) * 1024 + sl0;
    const unsigned short* Bp1 = Bw + (size_t)(tn * 128 + r1) * 1024 + sl1;

    f32x4 acc[4][4] = {};
    const int fread = (lr >> 1) & 3;

    gload16(Ap0, &As[0][c0 * 512]);
    gload16(Ap1, &As[0][c1 * 512]);
    gload16(Bp0, &Bs[0][c0 * 512]);
    gload16(Bp1, &Bs[0][c1 * 512]);

    int cur = 0;
    for (int k0 = 0; k0 < 1024; k0 += 32) {
        const int nk = (k0 + 32 < 1024) ? k0 + 32 : k0;
        gload16(Ap0 + nk, &As[cur ^ 1][c0 * 512]);
        gload16(Ap1 + nk, &As[cur ^ 1][c1 * 512]);
        gload16(Bp0 + nk, &Bs[cur ^ 1][c0 * 512]);
        gload16(Bp1 + nk, &Bs[cur ^ 1][c1 * 512]);
        asm volatile("s_waitcnt vmcnt(4)" ::: "memory");
        __builtin_amdgcn_s_barrier();
        __builtin_amdgcn_sched_barrier(0);

        const short* Ac  = As[cur];
        const short* Bc2 = Bs[cur];
        bf16x8 af[4], bfv[4];
        #pragma unroll
        for (int m = 0; m < 4; m++) {
            const int row = wm + m * 16 + lr;
            af[m] = *(const bf16x8*)&Ac[row * 32 + (lg ^ fread) * 8];
        }
        #pragma unroll
        for (int n = 0; n < 4; n++) {
            const int row = wn + n * 16 + lr;
            bfv[n] = *(const bf16x8*)&Bc2[row * 32 + (lg ^ fread) * 8];
        }
        #pragma unroll
        for (int m = 0; m < 4; m++)
            #pragma unroll
            for (int n = 0; n < 4; n++)
                acc[m][n] = mfma16(af[m], bfv[n], acc[m][n]);

        asm volatile("s_waitcnt lgkmcnt(0)" ::: "memory");
        __builtin_amdgcn_sched_barrier(0);
        __builtin_amdgcn_s_barrier();
        cur ^= 1;
    }
    asm volatile("s_waitcnt vmcnt(0)" ::: "memory");

    #pragma unroll
    for (int n = 0; n < 4; n++) {
        const int col = tn * 128 + wn + n * 16 + lr;
        const float bv = bias[col];
        #pragma unroll
        for (int m = 0; m < 4; m++) {
            const int row0 = tm * 128 + wm + m * 16 + lg * 4;
            #pragma unroll
            for (int r = 0; r < 4; r++)
                Y[(size_t)(row0 + r) * 1024 + col] = acc[m][n][r] + bv;
        }
    }
}

// ---- flash attention: R10/R12 version verbatim ----
__global__ __launch_bounds__(512, 2) void attn_fwd(
    const unsigned short* __restrict__ Q, const unsigned short* __restrict__ Kg,
    const unsigned short* __restrict__ Vtg, unsigned short* __restrict__ ctx)
{
    __shared__ short Ks[2][4096];
    __shared__ short Vs[2][4096];

    const int tid = threadIdx.x, lane = tid & 63, w = tid >> 6;   // w in 0..7
    const int l31 = lane & 31, hi = lane >> 5;

    const int blk = blockIdx.x;
    const int idx = blk >> 3;
    const int bh = (blk & 7) * 4 + (idx >> 3);
    const int qt = idx & 7;

    const unsigned short* Qb = Q   + (size_t)bh * Sc * HDc;
    const unsigned short* Kb = Kg  + (size_t)bh * Sc * HDc;
    const unsigned short* Vb = Vtg + (size_t)bh * HDc * Sc;

    const int qbase = qt * 256 + w * 32;
    bf16x8 qf[4];
    {
        const size_t qr = (size_t)(qbase + l31) * HDc + hi * 8;
        #pragma unroll
        for (int kk = 0; kk < 4; kk++)
            qf[kk] = *(const bf16x8*)&Qb[qr + kk * 16];
    }

    const int srow  = w * 8 + (lane >> 3);
    const int sslot = ((lane & 7) ^ (lane >> 3)) * 8;
    const unsigned short* Kst = Kb + (size_t)srow * HDc + sslot;
    const unsigned short* Vst = Vb + (size_t)srow * Sc + sslot;

    const int swk = lane & 7;

    const f32x16 Z = {};
    f32x16 acc0 = {}, acc1 = {}, accl = {};

    union { unsigned int u[4]; bf16x8 v; } ones;
    ones.u[0] = ones.u[1] = ones.u[2] = ones.u[3] = 0x3F803F80u;

    gload16(Kst, &Ks[0][w * 512]);
    gload16(Vst, &Vs[0][w * 512]);

    int cur = 0;
    for (int kt = 0; kt < 32; ++kt) {
        {
            const int nxt = kt < 31 ? kt + 1 : 31;
            gload16(Kst + (size_t)nxt * 4096, &Ks[cur ^ 1][w * 512]);
            gload16(Vst + nxt * 64,           &Vs[cur ^ 1][w * 512]);
        }
        asm volatile("s_waitcnt vmcnt(2)" ::: "memory");
        __builtin_amdgcn_s_barrier();
        __builtin_amdgcn_sched_barrier(0);

        const short* Kc = Ks[cur];
        const short* Vc = Vs[cur];

        f32x16 sf0, sf1;
        __builtin_amdgcn_s_setprio(1);
        {
            const int sl = (hi ^ swk) * 8;
            bf16x8 a0 = *(const bf16x8*)&Kc[l31 * 64 + sl];
            bf16x8 a1 = *(const bf16x8*)&Kc[(32 + l31) * 64 + sl];
            sf0 = mfma32(a0, qf[0], Z);
            sf1 = mfma32(a1, qf[0], Z);
        }
        #pragma unroll
        for (int kk = 1; kk < 4; kk++) {
            const int sl = ((2 * kk + hi) ^ swk) * 8;
            bf16x8 a0 = *(const bf16x8*)&Kc[l31 * 64 + sl];
            bf16x8 a1 = *(const bf16x8*)&Kc[(32 + l31) * 64 + sl];
            sf0 = mfma32(a0, qf[kk], sf0);
            sf1 = mfma32(a1, qf[kk], sf1);
        }
        __builtin_amdgcn_s_setprio(0);

        unsigned int p0[8], p1[8];
        #pragma unroll
        for (int j = 0; j < 8; j++) {
            const float a0 = __builtin_amdgcn_exp2f(sf0[2 * j]);
            const float a1 = __builtin_amdgcn_exp2f(sf0[2 * j + 1]);
            const float b0 = __builtin_amdgcn_exp2f(sf1[2 * j]);
            const float b1 = __builtin_amdgcn_exp2f(sf1[2 * j + 1]);
            asm("v_cvt_pk_bf16_f32 %0, %1, %2" : "=v"(p0[j]) : "v"(a0), "v"(a1));
            asm("v_cvt_pk_bf16_f32 %0, %1, %2" : "=v"(p1[j]) : "v"(b0), "v"(b1));
        }

        __builtin_amdgcn_s_setprio(1);
        #pragma unroll
        for (int m = 0; m < 4; m++) {
            const unsigned int* pw = (m < 2) ? &p0[(m & 1) * 4] : &p1[(m & 1) * 4];
            union { unsigned int u[4]; bf16x8 v; } af;
            af.u[0] = pw[0]; af.u[1] = pw[1]; af.u[2] = pw[2]; af.u[3] = pw[3];
            const int sl = ((2 * m + hi) ^ swk) * 8;
            bf16x8 b0 = *(const bf16x8*)&Vc[l31 * 64 + sl];
            bf16x8 b1 = *(const bf16x8*)&Vc[(32 + l31) * 64 + sl];
            acc0 = mfma32(af.v, b0, acc0);
            acc1 = mfma32(af.v, b1, acc1);
            accl = mfma32(af.v, ones.v, accl);
        }
        __builtin_amdgcn_s_setprio(0);

        asm volatile("s_waitcnt lgkmcnt(0)" ::: "memory");
        __builtin_amdgcn_sched_barrier(0);
        __builtin_amdgcn_s_barrier();
        cur ^= 1;
    }
    asm volatile("s_waitcnt vmcnt(0)" ::: "memory");

    const int b_ = bh >> 4, hh = bh & 15;
    #pragma unroll
    for (int r = 0; r < 16; r++) {
        const int qr = (r & 3) + 8 * (r >> 2) + 4 * hi;
        const float lv = __builtin_amdgcn_rcpf(accl[r]);
        const int sq = qbase + qr;
        unsigned short* co = &ctx[((size_t)(b_ * Sc + sq)) * Dc + (size_t)hh * HDc + l31];
        co[0]  = f2bf(acc0[r] * lv);
        co[32] = f2bf(acc1[r] * lv);
    }
}

extern "C" void kernel_launch(void* const* d_in, const int* in_sizes, int n_in,
                              void* d_out, int out_size, void* d_ws, size_t ws_size,
                              hipStream_t stream)
{
    const float* query = (const float*)d_in[0];
    const float* key   = (const float*)d_in[1];
    const float* value = (const float*)d_in[2];
    const float* Wq = (const float*)d_in[3];
    const float* bq = (const float*)d_in[4];
    const float* Wk = (const float*)d_in[5];
    const float* bk = (const float*)d_in[6];
    const float* Wv = (const float*)d_in[7];
    const float* bv = (const float*)d_in[8];
    const float* Wo = (const float*)d_in[9];
    const float* bo = (const float*)d_in[10];

    constexpr size_t W = 1048576, AE = 4194304;
    unsigned short* wqb = (unsigned short*)d_ws;
    unsigned short* wkb = wqb + W;
    unsigned short* wvb = wkb + W;
    unsigned short* wob = wvb + W;
    unsigned short* Qh  = wob + W;
    unsigned short* Kh  = Qh + AE;
    unsigned short* Vth = Kh + AE;
    unsigned short* cx  = Vth + AE;

    cvt_w<<<2048, 256, 0, stream>>>(Wq, Wk, Wv, Wo, wqb, wkb, wvb, wob);
    qkv_gemm<<<192, 512, 0, stream>>>(query, key, value, wqb, wkb, wvb,
                                      bq, bk, bv, Qh, Kh, Vth);
    attn_fwd<<<256, 512, 0, stream>>>(Qh, Kh, Vth, cx);
    out_gemm<<<256, 256, 0, stream>>>(cx, wob, bo, (float*)d_out);
}

// Round 14
// 119.575 us; speedup vs baseline: 1.1766x; 1.1766x over previous
//
#include <hip/hip_runtime.h>
#include <hip/hip_bf16.h>

#define DEVFN __device__ __forceinline__

typedef __attribute__((ext_vector_type(8))) short bf16x8;   // 8 bf16 = 4 VGPR
typedef __attribute__((ext_vector_type(4))) float f32x4;
typedef __attribute__((ext_vector_type(16))) float f32x16;

constexpr int Bc = 2, Sc = 2048, Dc = 1024, Hc = 16, HDc = 64;
constexpr float SCALEc = 0.125f;  // HD^-0.5
constexpr float LOG2E  = 1.44269504088896340736f;

DEVFN unsigned short f2bf(float f) {  // RNE fp32 -> bf16
    union { float f; unsigned int u; } x; x.f = f;
    return (unsigned short)((x.u + 0x7fffu + ((x.u >> 16) & 1u)) >> 16);
}

DEVFN f32x4 mfma16(bf16x8 a, bf16x8 b, f32x4 c) {
    return __builtin_amdgcn_mfma_f32_16x16x32_bf16(a, b, c, 0, 0, 0);
}
DEVFN f32x16 mfma32(bf16x8 a, bf16x8 b, f32x16 c) {
    return __builtin_amdgcn_mfma_f32_32x32x16_bf16(a, b, c, 0, 0, 0);
}

DEVFN void gload16(const void* g, void* l) {  // async global->LDS, dest = base + lane*16
    __builtin_amdgcn_global_load_lds((const __attribute__((address_space(1))) void*)g,
                                     (__attribute__((address_space(3))) void*)l, 16, 0, 0);
}

// ---- weights fp32 -> bf16 (4 x 1M elems) ----
__global__ __launch_bounds__(256) void cvt_w(
    const float* __restrict__ wq, const float* __restrict__ wk,
    const float* __restrict__ wv, const float* __restrict__ wo,
    unsigned short* __restrict__ wqb, unsigned short* __restrict__ wkb,
    unsigned short* __restrict__ wvb, unsigned short* __restrict__ wob)
{
    const unsigned t = blockIdx.x * 256 + threadIdx.x;   // 524288 threads
    const unsigned which = t >> 17, local = t & ((1u << 17) - 1);
    const float* s = which == 0 ? wq : which == 1 ? wk : which == 2 ? wv : wo;
    unsigned short* d = which == 0 ? wqb : which == 1 ? wkb : which == 2 ? wvb : wob;
    const size_t off = (size_t)local * 8;
    float4 v0 = *(const float4*)(s + off);
    float4 v1 = *(const float4*)(s + off + 4);
    unsigned short t8[8] = {f2bf(v0.x), f2bf(v0.y), f2bf(v0.z), f2bf(v0.w),
                            f2bf(v1.x), f2bf(v1.y), f2bf(v1.z), f2bf(v1.w)};
    *(uint4*)(d + off) = *(const uint4*)t8;
}

// ---- fused QKV projection, R12 structure with BK=64 (two 32-k sub-buffers, each the
// exact R12 layout). A fp32 reg-staged (parity fE/fO), B bf16 via global_load_lds.
// 16 steps, vmcnt(20) = A(t+1)8 + B(t+1)4 + A(t+2)8. Q pre-scaled by SCALE*log2e.
// g<2: out [B,H,S,HD]; g==2: out [B,H,HD,S], k-bits 2<->3 swapped per 16-group.
__global__ __launch_bounds__(256, 2) void qkv_gemm(
    const float* __restrict__ Aq, const float* __restrict__ Ak, const float* __restrict__ Av,
    const unsigned short* __restrict__ Wqb, const unsigned short* __restrict__ Wkb,
    const unsigned short* __restrict__ Wvb,
    const float* __restrict__ bqp, const float* __restrict__ bkp, const float* __restrict__ bvp,
    unsigned short* __restrict__ Qo, unsigned short* __restrict__ Ko, unsigned short* __restrict__ Vto)
{
    __shared__ short As[16384];   // [buf][half][128 rows][32 k] = 2*2*4096
    __shared__ short Bs[16384];

    const int g = blockIdx.x >> 8;
    const float* A = g == 0 ? Aq : g == 1 ? Ak : Av;
    const unsigned short* Bw = g == 0 ? Wqb : g == 1 ? Wkb : Wvb;
    const float* bias = g == 0 ? bqp : g == 1 ? bkp : bvp;
    const float scale = g == 0 ? SCALEc * LOG2E : 1.0f;

    const int tid = threadIdx.x, lane = tid & 63, w = tid >> 6;
    const int lr = lane & 15, lg = lane >> 4;
    const int bid = blockIdx.x & 255;
    const int tm = bid & 31, tn = bid >> 5;
    const int wm = (w >> 1) * 64, wn = (w & 1) * 64;

    // chunk c: lane -> row c*16+(l>>2), swizzled 8-elem slot (l&3)^((row>>1)&3)
    const int c0 = 2 * w, c1 = 2 * w + 1;
    const int r0 = c0 * 16 + (lane >> 2), r1 = c1 * 16 + (lane >> 2);
    const int s0 = (lane & 3) ^ ((r0 >> 1) & 3), s1 = (lane & 3) ^ ((r1 >> 1) & 3);
    const float* Afp0 = A + (size_t)(tm * 128 + r0) * 1024 + s0 * 8;
    const float* Afp1 = A + (size_t)(tm * 128 + r1) * 1024 + s1 * 8;
    const unsigned short* Bp0 = Bw + (size_t)(tn * 128 + r0) * 1024 + s0 * 8;
    const unsigned short* Bp1 = Bw + (size_t)(tn * 128 + r1) * 1024 + s1 * 8;
    // linear write dests (source carries the swizzle)
    const int aw0 = c0 * 512 + lane * 8;
    const int aw1 = c1 * 512 + lane * 8;

    f32x4 acc[4][4] = {};
    const int fread = (lr >> 1) & 3;

    float4 fE[8], fO[8];   // A reg tiles (parity): [0..3] half0 (rows r0,r1), [4..7] half1

#define LOAD_A(R, KO)                                                            \
    R[0] = *(const float4*)(Afp0 + (KO));      R[1] = *(const float4*)(Afp0 + (KO) + 4);  \
    R[2] = *(const float4*)(Afp1 + (KO));      R[3] = *(const float4*)(Afp1 + (KO) + 4);  \
    R[4] = *(const float4*)(Afp0 + (KO) + 32); R[5] = *(const float4*)(Afp0 + (KO) + 36); \
    R[6] = *(const float4*)(Afp1 + (KO) + 32); R[7] = *(const float4*)(Afp1 + (KO) + 36);

#define CVT_PAIR(DST, Fa, Fb)                                                    \
    {                                                                            \
        unsigned int q0, q1, q2, q3;                                             \
        asm("v_cvt_pk_bf16_f32 %0,%1,%2" : "=v"(q0) : "v"(Fa.x), "v"(Fa.y));     \
        asm("v_cvt_pk_bf16_f32 %0,%1,%2" : "=v"(q1) : "v"(Fa.z), "v"(Fa.w));     \
        asm("v_cvt_pk_bf16_f32 %0,%1,%2" : "=v"(q2) : "v"(Fb.x), "v"(Fb.y));     \
        asm("v_cvt_pk_bf16_f32 %0,%1,%2" : "=v"(q3) : "v"(Fb.z), "v"(Fb.w));     \
        *(uint4*)(DST) = (uint4){q0, q1, q2, q3};                                \
    }

#define CVT_A(R, BUF)                                                            \
    CVT_PAIR(&As[(BUF) * 8192 + aw0],        R[0], R[1])                         \
    CVT_PAIR(&As[(BUF) * 8192 + aw1],        R[2], R[3])                         \
    CVT_PAIR(&As[(BUF) * 8192 + 4096 + aw0], R[4], R[5])                         \
    CVT_PAIR(&As[(BUF) * 8192 + 4096 + aw1], R[6], R[7])

    // ---- prologue: B(0) 4 gloads; A(0)->fE->As[0]; A(1)->fO ----
    gload16(Bp0,      &Bs[c0 * 512]);
    gload16(Bp1,      &Bs[c1 * 512]);
    gload16(Bp0 + 32, &Bs[4096 + c0 * 512]);
    gload16(Bp1 + 32, &Bs[4096 + c1 * 512]);
    LOAD_A(fE, 0)
    CVT_A(fE, 0)
    LOAD_A(fO, 64)
    asm volatile("s_waitcnt lgkmcnt(0)" ::: "memory");

#define QKV_STEP(KT, P, FI, FC)                                                  \
    {                                                                            \
        const int k1 = ((KT) < 15) ? ((KT) + 1) * 64 : 960;                      \
        const int k2 = ((KT) < 14) ? ((KT) + 2) * 64 : 960;                      \
        gload16(Bp0 + k1,      &Bs[((P) ^ 1) * 8192 + c0 * 512]);                \
        gload16(Bp1 + k1,      &Bs[((P) ^ 1) * 8192 + c1 * 512]);                \
        gload16(Bp0 + k1 + 32, &Bs[((P) ^ 1) * 8192 + 4096 + c0 * 512]);         \
        gload16(Bp1 + k1 + 32, &Bs[((P) ^ 1) * 8192 + 4096 + c1 * 512]);         \
        LOAD_A(FI, k2)                                                           \
        asm volatile("s_waitcnt vmcnt(20)" ::: "memory");                        \
        __builtin_amdgcn_s_barrier();                                            \
        __builtin_amdgcn_sched_barrier(0);                                       \
        _Pragma("unroll")                                                        \
        for (int kh2 = 0; kh2 < 2; kh2++) {                                      \
            const short* Ac  = &As[(P) * 8192 + kh2 * 4096];                     \
            const short* Bc2 = &Bs[(P) * 8192 + kh2 * 4096];                     \
            bf16x8 af[4], bfv[4];                                                \
            _Pragma("unroll")                                                    \
            for (int m = 0; m < 4; m++) {                                        \
                const int row = wm + m * 16 + lr;                                \
                af[m] = *(const bf16x8*)&Ac[row * 32 + (lg ^ fread) * 8];        \
            }                                                                    \
            _Pragma("unroll")                                                    \
            for (int n = 0; n < 4; n++) {                                        \
                const int row = wn + n * 16 + lr;                                \
                bfv[n] = *(const bf16x8*)&Bc2[row * 32 + (lg ^ fread) * 8];      \
            }                                                                    \
            _Pragma("unroll")                                                    \
            for (int m = 0; m < 4; m++)                                          \
                _Pragma("unroll")                                                \
                for (int n = 0; n < 4; n++)                                      \
                    acc[m][n] = mfma16(af[m], bfv[n], acc[m][n]);                \
        }                                                                        \
        CVT_A(FC, (P) ^ 1)                                                       \
        asm volatile("s_waitcnt lgkmcnt(0)" ::: "memory");                       \
        __builtin_amdgcn_sched_barrier(0);                                       \
        __builtin_amdgcn_s_barrier();                                            \
    }

    for (int kt = 0; kt < 16; kt += 2) {
        QKV_STEP(kt,     0, fE, fO)
        QKV_STEP(kt + 1, 1, fO, fE)
    }
    asm volatile("s_waitcnt vmcnt(0)" ::: "memory");   // drain clamped dups
#undef QKV_STEP
#undef LOAD_A
#undef CVT_A
#undef CVT_PAIR

    if (g < 2) {
        unsigned short* Y = g == 0 ? Qo : Ko;
        #pragma unroll
        for (int n = 0; n < 4; n++) {
            const int col = tn * 128 + wn + n * 16 + lr;
            const float bv = bias[col];
            const int hh = col >> 6, hd = col & 63;
            #pragma unroll
            for (int m = 0; m < 4; m++) {
                const int row0 = tm * 128 + wm + m * 16 + lg * 4;
                const int b_ = row0 >> 11, sQ = row0 & 2047;
                #pragma unroll
                for (int r = 0; r < 4; r++) {
                    const float val = (acc[m][n][r] + bv) * scale;
                    Y[(((size_t)(b_ * Hc + hh)) * Sc + (sQ + r)) * HDc + hd] = f2bf(val);
                }
            }
        }
    } else {
        #pragma unroll
        for (int n = 0; n < 4; n++) {
            const int col = tn * 128 + wn + n * 16 + lr;
            const float bv = bias[col];
            const int hh = col >> 6, hd = col & 63;
            #pragma unroll
            for (int m = 0; m < 4; m++) {
                const int row0 = tm * 128 + wm + m * 16 + lg * 4;
                const int b_ = row0 >> 11, sQ = row0 & 2047;
                const int sQp = (sQ & ~12) | ((sQ & 4) << 1) | ((sQ & 8) >> 1);  // k bits 2<->3
                unsigned long long pk = 0;
                #pragma unroll
                for (int r = 0; r < 4; r++)
                    pk |= (unsigned long long)f2bf(acc[m][n][r] + bv) << (16 * r);
                *(unsigned long long*)&Vto[(((size_t)(b_ * Hc + hh)) * HDc + hd) * Sc + sQp] = pk;
            }
        }
    }
}

// ---- output projection: R12 dbuf version (bf16 A from attn, bf16 Wo) ----
__global__ __launch_bounds__(256) void out_gemm(
    const unsigned short* __restrict__ Ab, const unsigned short* __restrict__ Bw,
    const float* __restrict__ bias, float* __restrict__ Y)
{
    __shared__ short As[2][4096];
    __shared__ short Bs[2][4096];
    const int tid = threadIdx.x, lane = tid & 63, w = tid >> 6;
    const int lr = lane & 15, lg = lane >> 4;
    const int tm = blockIdx.x & 31, tn = blockIdx.x >> 5;
    const int wm = (w >> 1) * 64, wn = (w & 1) * 64;

    const int c0 = 2 * w, c1 = 2 * w + 1;
    const int r0 = c0 * 16 + (lane >> 2), r1 = c1 * 16 + (lane >> 2);
    const int sl0 = ((lane & 3) ^ ((r0 >> 1) & 3)) * 8, sl1 = ((lane & 3) ^ ((r1 >> 1) & 3)) * 8;
    const unsigned short* Ap0 = Ab + (size_t)(tm * 128 + r0) * 1024 + sl0;
    const unsigned short* Ap1 = Ab + (size_t)(tm * 128 + r1) * 1024 + sl1;
    const unsigned short* Bp0 = Bw + (size_t)(tn * 128 + r0) * 1024 + sl0;
    const unsigned short* Bp1 = Bw + (size_t)(tn * 128 + r1) * 1024 + sl1;

    f32x4 acc[4][4] = {};
    const int fread = (lr >> 1) & 3;

    gload16(Ap0, &As[0][c0 * 512]);
    gload16(Ap1, &As[0][c1 * 512]);
    gload16(Bp0, &Bs[0][c0 * 512]);
    gload16(Bp1, &Bs[0][c1 * 512]);

    int cur = 0;
    for (int k0 = 0; k0 < 1024; k0 += 32) {
        const int nk = (k0 + 32 < 1024) ? k0 + 32 : k0;
        gload16(Ap0 + nk, &As[cur ^ 1][c0 * 512]);
        gload16(Ap1 + nk, &As[cur ^ 1][c1 * 512]);
        gload16(Bp0 + nk, &Bs[cur ^ 1][c0 * 512]);
        gload16(Bp1 + nk, &Bs[cur ^ 1][c1 * 512]);
        asm volatile("s_waitcnt vmcnt(4)" ::: "memory");
        __builtin_amdgcn_s_barrier();
        __builtin_amdgcn_sched_barrier(0);

        const short* Ac  = As[cur];
        const short* Bc2 = Bs[cur];
        bf16x8 af[4], bfv[4];
        #pragma unroll
        for (int m = 0; m < 4; m++) {
            const int row = wm + m * 16 + lr;
            af[m] = *(const bf16x8*)&Ac[row * 32 + (lg ^ fread) * 8];
        }
        #pragma unroll
        for (int n = 0; n < 4; n++) {
            const int row = wn + n * 16 + lr;
            bfv[n] = *(const bf16x8*)&Bc2[row * 32 + (lg ^ fread) * 8];
        }
        #pragma unroll
        for (int m = 0; m < 4; m++)
            #pragma unroll
            for (int n = 0; n < 4; n++)
                acc[m][n] = mfma16(af[m], bfv[n], acc[m][n]);

        asm volatile("s_waitcnt lgkmcnt(0)" ::: "memory");
        __builtin_amdgcn_sched_barrier(0);
        __builtin_amdgcn_s_barrier();
        cur ^= 1;
    }
    asm volatile("s_waitcnt vmcnt(0)" ::: "memory");

    #pragma unroll
    for (int n = 0; n < 4; n++) {
        const int col = tn * 128 + wn + n * 16 + lr;
        const float bv = bias[col];
        #pragma unroll
        for (int m = 0; m < 4; m++) {
            const int row0 = tm * 128 + wm + m * 16 + lg * 4;
            #pragma unroll
            for (int r = 0; r < 4; r++)
                Y[(size_t)(row0 + r) * 1024 + col] = acc[m][n][r] + bv;
        }
    }
}

// ---- flash attention: R12 structure with KVBLK=128 (two 64-k subs per barrier pair).
// 8 waves/block, 32x32x16 MFMA, in-lane P, V pre-permuted (k bits 2<->3 per 16-group),
// accl ones-column MFMA, no-max exp2 softmax, XOR-swizzled LDS, vmcnt(4) dbuf.
__global__ __launch_bounds__(512, 2) void attn_fwd(
    const unsigned short* __restrict__ Q, const unsigned short* __restrict__ Kg,
    const unsigned short* __restrict__ Vtg, unsigned short* __restrict__ ctx)
{
    __shared__ short Ks[2][8192];   // [buf][128 krows][64 hd], swizzled content
    __shared__ short Vs[2][8192];   // [buf][64 hd][128 k], swizzled content

    const int tid = threadIdx.x, lane = tid & 63, w = tid >> 6;   // w in 0..7
    const int l31 = lane & 31, hi = lane >> 5;

    const int blk = blockIdx.x;
    const int idx = blk >> 3;
    const int bh = (blk & 7) * 4 + (idx >> 3);
    const int qt = idx & 7;

    const unsigned short* Qb = Q   + (size_t)bh * Sc * HDc;
    const unsigned short* Kb = Kg  + (size_t)bh * Sc * HDc;
    const unsigned short* Vb = Vtg + (size_t)bh * HDc * Sc;

    const int qbase = qt * 256 + w * 32;
    bf16x8 qf[4];
    {
        const size_t qr = (size_t)(qbase + l31) * HDc + hi * 8;
        #pragma unroll
        for (int kk = 0; kk < 4; kk++)
            qf[kk] = *(const bf16x8*)&Qb[qr + kk * 16];
    }

    // K staging: wave w stages rows w*16..+15 (2 gloads); source pre-swizzled by row&7
    const int krow = w * 16 + (lane >> 3);
    const int ksl  = ((lane & 7) ^ (lane >> 3)) * 8;     // (row&7) == lane>>3 for both gloads
    const unsigned short* Kst = Kb + (size_t)krow * HDc + ksl;
    // V staging: wave w stages hd rows w*8..+7 (2 gloads of 4 rows x 256B);
    // row&7 = (lane>>4) for gload1, (lane>>4)+4 for gload2
    const int vrow = w * 8 + (lane >> 4);
    const int vc1  = ((lane & 15) ^ (lane >> 4)) * 8;
    const int vc2  = ((lane & 15) ^ ((lane >> 4) + 4)) * 8;
    const unsigned short* Vst1 = Vb + (size_t)vrow * Sc + vc1;
    const unsigned short* Vst2 = Vb + (size_t)(vrow + 4) * Sc + vc2;

    const int swk = lane & 7;

    const f32x16 Z = {};
    f32x16 acc0 = {}, acc1 = {}, accl = {};

    union { unsigned int u[4]; bf16x8 v; } ones;
    ones.u[0] = ones.u[1] = ones.u[2] = ones.u[3] = 0x3F803F80u;

    // prologue: tile 0 into buf 0 (2 K + 2 V gloads per lane)
    gload16(Kst,             &Ks[0][w * 1024]);
    gload16(Kst + 512,       &Ks[0][w * 1024 + 512]);   // rows +8 (8*64 elems)
    gload16(Vst1,            &Vs[0][w * 1024]);
    gload16(Vst2,            &Vs[0][w * 1024 + 512]);   // hd rows +4

    int cur = 0;
    for (int kt = 0; kt < 16; ++kt) {
        {
            const int nxt = kt < 15 ? kt + 1 : 15;
            gload16(Kst + (size_t)nxt * 8192,       &Ks[cur ^ 1][w * 1024]);
            gload16(Kst + (size_t)nxt * 8192 + 512, &Ks[cur ^ 1][w * 1024 + 512]);
            gload16(Vst1 + nxt * 128,               &Vs[cur ^ 1][w * 1024]);
            gload16(Vst2 + nxt * 128,               &Vs[cur ^ 1][w * 1024 + 512]);
        }
        asm volatile("s_waitcnt vmcnt(4)" ::: "memory");
        __builtin_amdgcn_s_barrier();
        __builtin_amdgcn_sched_barrier(0);

        const short* Kc = Ks[cur];
        const short* Vc = Vs[cur];

        #pragma unroll
        for (int sub = 0; sub < 2; sub++) {
            const int kro = sub * 64;     // K row offset
            const int vco = sub * 8;      // V chunk offset (64 k = 8 chunks)

            // S^T = K·Q^T: D col = q = l31, rows = k (regs)
            f32x16 sf0, sf1;
            __builtin_amdgcn_s_setprio(1);
            {
                const int sl = (hi ^ swk) * 8;
                bf16x8 a0 = *(const bf16x8*)&Kc[(kro + l31) * 64 + sl];
                bf16x8 a1 = *(const bf16x8*)&Kc[(kro + 32 + l31) * 64 + sl];
                sf0 = mfma32(a0, qf[0], Z);
                sf1 = mfma32(a1, qf[0], Z);
            }
            #pragma unroll
            for (int kk = 1; kk < 4; kk++) {
                const int sl = ((2 * kk + hi) ^ swk) * 8;
                bf16x8 a0 = *(const bf16x8*)&Kc[(kro + l31) * 64 + sl];
                bf16x8 a1 = *(const bf16x8*)&Kc[(kro + 32 + l31) * 64 + sl];
                sf0 = mfma32(a0, qf[kk], sf0);
                sf1 = mfma32(a1, qf[kk], sf1);
            }
            __builtin_amdgcn_s_setprio(0);

            // no-max softmax: P = exp2(s~); C/D reg r -> k = (r&3)+8*(r>>2)+4*hi
            unsigned int p0[8], p1[8];
            #pragma unroll
            for (int j = 0; j < 8; j++) {
                const float a0 = __builtin_amdgcn_exp2f(sf0[2 * j]);
                const float a1 = __builtin_amdgcn_exp2f(sf0[2 * j + 1]);
                const float b0 = __builtin_amdgcn_exp2f(sf1[2 * j]);
                const float b1 = __builtin_amdgcn_exp2f(sf1[2 * j + 1]);
                asm("v_cvt_pk_bf16_f32 %0, %1, %2" : "=v"(p0[j]) : "v"(a0), "v"(a1));
                asm("v_cvt_pk_bf16_f32 %0, %1, %2" : "=v"(p1[j]) : "v"(b0), "v"(b1));
            }

            // PV: A = lane's own P pairs; B = one b128/row at chunk (vco+2m+hi)^swk
            __builtin_amdgcn_s_setprio(1);
            #pragma unroll
            for (int m = 0; m < 4; m++) {
                const unsigned int* pw = (m < 2) ? &p0[(m & 1) * 4] : &p1[(m & 1) * 4];
                union { unsigned int u[4]; bf16x8 v; } af;
                af.u[0] = pw[0]; af.u[1] = pw[1]; af.u[2] = pw[2]; af.u[3] = pw[3];
                const int sl = ((vco + 2 * m + hi) ^ swk) * 8;
                bf16x8 b0 = *(const bf16x8*)&Vc[l31 * 128 + sl];
                bf16x8 b1 = *(const bf16x8*)&Vc[(32 + l31) * 128 + sl];
                acc0 = mfma32(af.v, b0, acc0);
                acc1 = mfma32(af.v, b1, acc1);
                accl = mfma32(af.v, ones.v, accl);
            }
            __builtin_amdgcn_s_setprio(0);
        }

        asm volatile("s_waitcnt lgkmcnt(0)" ::: "memory");
        __builtin_amdgcn_sched_barrier(0);
        __builtin_amdgcn_s_barrier();
        cur ^= 1;
    }
    asm volatile("s_waitcnt vmcnt(0)" ::: "memory");

    const int b_ = bh >> 4, hh = bh & 15;
    #pragma unroll
    for (int r = 0; r < 16; r++) {
        const int qr = (r & 3) + 8 * (r >> 2) + 4 * hi;
        const float lv = __builtin_amdgcn_rcpf(accl[r]);
        const int sq = qbase + qr;
        unsigned short* co = &ctx[((size_t)(b_ * Sc + sq)) * Dc + (size_t)hh * HDc + l31];
        co[0]  = f2bf(acc0[r] * lv);
        co[32] = f2bf(acc1[r] * lv);
    }
}

extern "C" void kernel_launch(void* const* d_in, const int* in_sizes, int n_in,
                              void* d_out, int out_size, void* d_ws, size_t ws_size,
                              hipStream_t stream)
{
    const float* query = (const float*)d_in[0];
    const float* key   = (const float*)d_in[1];
    const float* value = (const float*)d_in[2];
    const float* Wq = (const float*)d_in[3];
    const float* bq = (const float*)d_in[4];
    const float* Wk = (const float*)d_in[5];
    const float* bk = (const float*)d_in[6];
    const float* Wv = (const float*)d_in[7];
    const float* bv = (const float*)d_in[8];
    const float* Wo = (const float*)d_in[9];
    const float* bo = (const float*)d_in[10];

    constexpr size_t W = 1048576, AE = 4194304;
    unsigned short* wqb = (unsigned short*)d_ws;
    unsigned short* wkb = wqb + W;
    unsigned short* wvb = wkb + W;
    unsigned short* wob = wvb + W;
    unsigned short* Qh  = wob + W;
    unsigned short* Kh  = Qh + AE;
    unsigned short* Vth = Kh + AE;
    unsigned short* cx  = Vth + AE;

    cvt_w<<<2048, 256, 0, stream>>>(Wq, Wk, Wv, Wo, wqb, wkb, wvb, wob);
    qkv_gemm<<<768, 256, 0, stream>>>(query, key, value, wqb, wkb, wvb,
                                      bq, bk, bv, Qh, Kh, Vth);
    attn_fwd<<<256, 512, 0, stream>>>(Qh, Kh, Vth, cx);
    out_gemm<<<256, 256, 0, stream>>>(cx, wob, bo, (float*)d_out);
}

// Round 15
// 115.647 us; speedup vs baseline: 1.2165x; 1.0340x over previous
//
#include <hip/hip_runtime.h>
#include <hip/hip_bf16.h>

#define DEVFN __device__ __forceinline__

typedef __attribute__((ext_vector_type(8))) short bf16x8;   // 8 bf16 = 4 VGPR
typedef __attribute__((ext_vector_type(4))) float f32x4;
typedef __attribute__((ext_vector_type(16))) float f32x16;

constexpr int Bc = 2, Sc = 2048, Dc = 1024, Hc = 16, HDc = 64;
constexpr float SCALEc = 0.125f;  // HD^-0.5
constexpr float LOG2E  = 1.44269504088896340736f;

DEVFN unsigned short f2bf(float f) {  // RNE fp32 -> bf16
    union { float f; unsigned int u; } x; x.f = f;
    return (unsigned short)((x.u + 0x7fffu + ((x.u >> 16) & 1u)) >> 16);
}

DEVFN f32x4 mfma16(bf16x8 a, bf16x8 b, f32x4 c) {
    return __builtin_amdgcn_mfma_f32_16x16x32_bf16(a, b, c, 0, 0, 0);
}
DEVFN f32x16 mfma32(bf16x8 a, bf16x8 b, f32x16 c) {
    return __builtin_amdgcn_mfma_f32_32x32x16_bf16(a, b, c, 0, 0, 0);
}

DEVFN void gload16(const void* g, void* l) {  // async global->LDS, dest = base + lane*16
    __builtin_amdgcn_global_load_lds((const __attribute__((address_space(1))) void*)g,
                                     (__attribute__((address_space(3))) void*)l, 16, 0, 0);
}

// ---- weights fp32 -> bf16 (4 x 1M elems) ----
__global__ __launch_bounds__(256) void cvt_w(
    const float* __restrict__ wq, const float* __restrict__ wk,
    const float* __restrict__ wv, const float* __restrict__ wo,
    unsigned short* __restrict__ wqb, unsigned short* __restrict__ wkb,
    unsigned short* __restrict__ wvb, unsigned short* __restrict__ wob)
{
    const unsigned t = blockIdx.x * 256 + threadIdx.x;   // 524288 threads
    const unsigned which = t >> 17, local = t & ((1u << 17) - 1);
    const float* s = which == 0 ? wq : which == 1 ? wk : which == 2 ? wv : wo;
    unsigned short* d = which == 0 ? wqb : which == 1 ? wkb : which == 2 ? wvb : wob;
    const size_t off = (size_t)local * 8;
    float4 v0 = *(const float4*)(s + off);
    float4 v1 = *(const float4*)(s + off + 4);
    unsigned short t8[8] = {f2bf(v0.x), f2bf(v0.y), f2bf(v0.z), f2bf(v0.w),
                            f2bf(v1.x), f2bf(v1.y), f2bf(v1.z), f2bf(v1.w)};
    *(uint4*)(d + off) = *(const uint4*)t8;
}

// ---- fused QKV projection (R12 structure, BK=32, fused fp32-A reg-staging) with
// XCD-aware block grouping: blocks sharing an A-panel (same g,tm) are id-consecutive
// within one XCD chunk of 96 -> A re-reads become same-XCD L2 hits.
// Q pre-scaled by SCALE*log2e. g<2: out [B,H,S,HD]; g==2: out [B,H,HD,S], k-bits
// 2<->3 swapped per 16-group (attention PV fragment permutation in memory).
__global__ __launch_bounds__(256, 3) void qkv_gemm(
    const float* __restrict__ Aq, const float* __restrict__ Ak, const float* __restrict__ Av,
    const unsigned short* __restrict__ Wqb, const unsigned short* __restrict__ Wkb,
    const unsigned short* __restrict__ Wvb,
    const float* __restrict__ bqp, const float* __restrict__ bkp, const float* __restrict__ bvp,
    unsigned short* __restrict__ Qo, unsigned short* __restrict__ Ko, unsigned short* __restrict__ Vto)
{
    __shared__ short As[2][4096];
    __shared__ short Bs[2][4096];

    // XCD-aware decode: lgid ordered g*256 + tm*8 + tn; XCD x gets lgids [96x, 96x+96)
    const int lgid = (blockIdx.x & 7) * 96 + (blockIdx.x >> 3);
    const int g = lgid >> 8;
    const int rem = lgid & 255;
    const int tm = rem >> 3, tn = rem & 7;

    const float* A = g == 0 ? Aq : g == 1 ? Ak : Av;
    const unsigned short* Bw = g == 0 ? Wqb : g == 1 ? Wkb : Wvb;
    const float* bias = g == 0 ? bqp : g == 1 ? bkp : bvp;
    const float scale = g == 0 ? SCALEc * LOG2E : 1.0f;

    const int tid = threadIdx.x, lane = tid & 63, w = tid >> 6;
    const int lr = lane & 15, lg = lane >> 4;
    const int wm = (w >> 1) * 64, wn = (w & 1) * 64;

    // chunk c: lane -> row c*16+(l>>2), swizzled 8-elem slot (l&3)^((row>>1)&3)
    const int c0 = 2 * w, c1 = 2 * w + 1;
    const int r0 = c0 * 16 + (lane >> 2), r1 = c1 * 16 + (lane >> 2);
    const int s0 = (lane & 3) ^ ((r0 >> 1) & 3), s1 = (lane & 3) ^ ((r1 >> 1) & 3);
    const float* Afp0 = A + (size_t)(tm * 128 + r0) * 1024 + s0 * 8;
    const float* Afp1 = A + (size_t)(tm * 128 + r1) * 1024 + s1 * 8;
    const unsigned short* Bp0 = Bw + (size_t)(tn * 128 + r0) * 1024 + s0 * 8;
    const unsigned short* Bp1 = Bw + (size_t)(tn * 128 + r1) * 1024 + s1 * 8;
    short* AW0[2] = {&As[0][c0 * 512 + lane * 8], &As[1][c0 * 512 + lane * 8]};
    short* AW1[2] = {&As[0][c1 * 512 + lane * 8], &As[1][c1 * 512 + lane * 8]};

    f32x4 acc[4][4] = {};
    const int fread = (lr >> 1) & 3;

    float4 fE[4], fO[4];   // A reg tiles: even steps in fE, odd in fO (static idx only)

    // ---- prologue: A(0)->fE->As[0]; B(0) gloads; A(1)->fO ----
    fE[0] = *(const float4*)(Afp0);     fE[1] = *(const float4*)(Afp0 + 4);
    fE[2] = *(const float4*)(Afp1);     fE[3] = *(const float4*)(Afp1 + 4);
    gload16(Bp0, &Bs[0][c0 * 512]);
    gload16(Bp1, &Bs[0][c1 * 512]);
    {
        unsigned int q0, q1, q2, q3;
        asm("v_cvt_pk_bf16_f32 %0,%1,%2" : "=v"(q0) : "v"(fE[0].x), "v"(fE[0].y));
        asm("v_cvt_pk_bf16_f32 %0,%1,%2" : "=v"(q1) : "v"(fE[0].z), "v"(fE[0].w));
        asm("v_cvt_pk_bf16_f32 %0,%1,%2" : "=v"(q2) : "v"(fE[1].x), "v"(fE[1].y));
        asm("v_cvt_pk_bf16_f32 %0,%1,%2" : "=v"(q3) : "v"(fE[1].z), "v"(fE[1].w));
        *(uint4*)AW0[0] = (uint4){q0, q1, q2, q3};
        asm("v_cvt_pk_bf16_f32 %0,%1,%2" : "=v"(q0) : "v"(fE[2].x), "v"(fE[2].y));
        asm("v_cvt_pk_bf16_f32 %0,%1,%2" : "=v"(q1) : "v"(fE[2].z), "v"(fE[2].w));
        asm("v_cvt_pk_bf16_f32 %0,%1,%2" : "=v"(q2) : "v"(fE[3].x), "v"(fE[3].y));
        asm("v_cvt_pk_bf16_f32 %0,%1,%2" : "=v"(q3) : "v"(fE[3].z), "v"(fE[3].w));
        *(uint4*)AW1[0] = (uint4){q0, q1, q2, q3};
    }
    fO[0] = *(const float4*)(Afp0 + 32); fO[1] = *(const float4*)(Afp0 + 36);
    fO[2] = *(const float4*)(Afp1 + 32); fO[3] = *(const float4*)(Afp1 + 36);
    asm volatile("s_waitcnt lgkmcnt(0)" ::: "memory");   // As[0] writes drained

    // per step KT (parity P): issue B(KT+1)->Bs[P^1], A(KT+2)->FI; wait vmcnt(10)=B(KT);
    // barrier; MFMA on As/Bs[P]; cvt FC (=A(KT+1)) -> As[P^1]; lgkm; barrier.
#define QKV_STEP(KT, P, FI, FC)                                                  \
    {                                                                            \
        const int k1 = ((KT) < 31) ? ((KT) + 1) * 32 : 992;                      \
        const int k2 = ((KT) < 30) ? ((KT) + 2) * 32 : 992;                      \
        gload16(Bp0 + k1, &Bs[(P) ^ 1][c0 * 512]);                               \
        gload16(Bp1 + k1, &Bs[(P) ^ 1][c1 * 512]);                               \
        FI[0] = *(const float4*)(Afp0 + k2); FI[1] = *(const float4*)(Afp0 + k2 + 4); \
        FI[2] = *(const float4*)(Afp1 + k2); FI[3] = *(const float4*)(Afp1 + k2 + 4); \
        asm volatile("s_waitcnt vmcnt(10)" ::: "memory");                        \
        __builtin_amdgcn_s_barrier();                                            \
        __builtin_amdgcn_sched_barrier(0);                                       \
        const short* Ac  = As[P];                                                \
        const short* Bc2 = Bs[P];                                                \
        bf16x8 af[4], bfv[4];                                                    \
        _Pragma("unroll")                                                        \
        for (int m = 0; m < 4; m++) {                                            \
            const int row = wm + m * 16 + lr;                                    \
            af[m] = *(const bf16x8*)&Ac[row * 32 + (lg ^ fread) * 8];            \
        }                                                                        \
        _Pragma("unroll")                                                        \
        for (int n = 0; n < 4; n++) {                                            \
            const int row = wn + n * 16 + lr;                                    \
            bfv[n] = *(const bf16x8*)&Bc2[row * 32 + (lg ^ fread) * 8];          \
        }                                                                        \
        _Pragma("unroll")                                                        \
        for (int m = 0; m < 4; m++)                                              \
            _Pragma("unroll")                                                    \
            for (int n = 0; n < 4; n++)                                          \
                acc[m][n] = mfma16(af[m], bfv[n], acc[m][n]);                    \
        {                                                                        \
            unsigned int q0, q1, q2, q3;                                         \
            asm("v_cvt_pk_bf16_f32 %0,%1,%2" : "=v"(q0) : "v"(FC[0].x), "v"(FC[0].y)); \
            asm("v_cvt_pk_bf16_f32 %0,%1,%2" : "=v"(q1) : "v"(FC[0].z), "v"(FC[0].w)); \
            asm("v_cvt_pk_bf16_f32 %0,%1,%2" : "=v"(q2) : "v"(FC[1].x), "v"(FC[1].y)); \
            asm("v_cvt_pk_bf16_f32 %0,%1,%2" : "=v"(q3) : "v"(FC[1].z), "v"(FC[1].w)); \
            *(uint4*)AW0[(P) ^ 1] = (uint4){q0, q1, q2, q3};                     \
            asm("v_cvt_pk_bf16_f32 %0,%1,%2" : "=v"(q0) : "v"(FC[2].x), "v"(FC[2].y)); \
            asm("v_cvt_pk_bf16_f32 %0,%1,%2" : "=v"(q1) : "v"(FC[2].z), "v"(FC[2].w)); \
            asm("v_cvt_pk_bf16_f32 %0,%1,%2" : "=v"(q2) : "v"(FC[3].x), "v"(FC[3].y)); \
            asm("v_cvt_pk_bf16_f32 %0,%1,%2" : "=v"(q3) : "v"(FC[3].z), "v"(FC[3].w)); \
            *(uint4*)AW1[(P) ^ 1] = (uint4){q0, q1, q2, q3};                     \
        }                                                                        \
        asm volatile("s_waitcnt lgkmcnt(0)" ::: "memory");                       \
        __builtin_amdgcn_sched_barrier(0);                                       \
        __builtin_amdgcn_s_barrier();                                            \
    }

    for (int kt = 0; kt < 32; kt += 2) {
        QKV_STEP(kt,     0, fE, fO)
        QKV_STEP(kt + 1, 1, fO, fE)
    }
    asm volatile("s_waitcnt vmcnt(0)" ::: "memory");   // drain clamped dup stages
#undef QKV_STEP

    if (g < 2) {
        unsigned short* Y = g == 0 ? Qo : Ko;
        #pragma unroll
        for (int n = 0; n < 4; n++) {
            const int col = tn * 128 + wn + n * 16 + lr;
            const float bv = bias[col];
            const int hh = col >> 6, hd = col & 63;
            #pragma unroll
            for (int m = 0; m < 4; m++) {
                const int row0 = tm * 128 + wm + m * 16 + lg * 4;
                const int b_ = row0 >> 11, sQ = row0 & 2047;
                #pragma unroll
                for (int r = 0; r < 4; r++) {
                    const float val = (acc[m][n][r] + bv) * scale;
                    Y[(((size_t)(b_ * Hc + hh)) * Sc + (sQ + r)) * HDc + hd] = f2bf(val);
                }
            }
        }
    } else {
        #pragma unroll
        for (int n = 0; n < 4; n++) {
            const int col = tn * 128 + wn + n * 16 + lr;
            const float bv = bias[col];
            const int hh = col >> 6, hd = col & 63;
            #pragma unroll
            for (int m = 0; m < 4; m++) {
                const int row0 = tm * 128 + wm + m * 16 + lg * 4;
                const int b_ = row0 >> 11, sQ = row0 & 2047;
                const int sQp = (sQ & ~12) | ((sQ & 4) << 1) | ((sQ & 8) >> 1);  // k bits 2<->3
                unsigned long long pk = 0;
                #pragma unroll
                for (int r = 0; r < 4; r++)
                    pk |= (unsigned long long)f2bf(acc[m][n][r] + bv) << (16 * r);
                *(unsigned long long*)&Vto[(((size_t)(b_ * Hc + hh)) * HDc + hd) * Sc + sQp] = pk;
            }
        }
    }
}

// ---- output projection: R12 dbuf + XCD-aware A-panel grouping ----
__global__ __launch_bounds__(256) void out_gemm(
    const unsigned short* __restrict__ Ab, const unsigned short* __restrict__ Bw,
    const float* __restrict__ bias, float* __restrict__ Y)
{
    __shared__ short As[2][4096];
    __shared__ short Bs[2][4096];
    const int tid = threadIdx.x, lane = tid & 63, w = tid >> 6;
    const int lr = lane & 15, lg = lane >> 4;
    // XCD-aware: lgid ordered tm*8 + tn; XCD x gets lgids [32x, 32x+32)
    const int lgid = (blockIdx.x & 7) * 32 + (blockIdx.x >> 3);
    const int tm = lgid >> 3, tn = lgid & 7;
    const int wm = (w >> 1) * 64, wn = (w & 1) * 64;

    const int c0 = 2 * w, c1 = 2 * w + 1;
    const int r0 = c0 * 16 + (lane >> 2), r1 = c1 * 16 + (lane >> 2);
    const int sl0 = ((lane & 3) ^ ((r0 >> 1) & 3)) * 8, sl1 = ((lane & 3) ^ ((r1 >> 1) & 3)) * 8;
    const unsigned short* Ap0 = Ab + (size_t)(tm * 128 + r0) * 1024 + sl0;
    const unsigned short* Ap1 = Ab + (size_t)(tm * 128 + r1) * 1024 + sl1;
    const unsigned short* Bp0 = Bw + (size_t)(tn * 128 + r0) * 1024 + sl0;
    const unsigned short* Bp1 = Bw + (size_t)(tn * 128 + r1) * 1024 + sl1;

    f32x4 acc[4][4] = {};
    const int fread = (lr >> 1) & 3;

    gload16(Ap0, &As[0][c0 * 512]);
    gload16(Ap1, &As[0][c1 * 512]);
    gload16(Bp0, &Bs[0][c0 * 512]);
    gload16(Bp1, &Bs[0][c1 * 512]);

    int cur = 0;
    for (int k0 = 0; k0 < 1024; k0 += 32) {
        const int nk = (k0 + 32 < 1024) ? k0 + 32 : k0;
        gload16(Ap0 + nk, &As[cur ^ 1][c0 * 512]);
        gload16(Ap1 + nk, &As[cur ^ 1][c1 * 512]);
        gload16(Bp0 + nk, &Bs[cur ^ 1][c0 * 512]);
        gload16(Bp1 + nk, &Bs[cur ^ 1][c1 * 512]);
        asm volatile("s_waitcnt vmcnt(4)" ::: "memory");
        __builtin_amdgcn_s_barrier();
        __builtin_amdgcn_sched_barrier(0);

        const short* Ac  = As[cur];
        const short* Bc2 = Bs[cur];
        bf16x8 af[4], bfv[4];
        #pragma unroll
        for (int m = 0; m < 4; m++) {
            const int row = wm + m * 16 + lr;
            af[m] = *(const bf16x8*)&Ac[row * 32 + (lg ^ fread) * 8];
        }
        #pragma unroll
        for (int n = 0; n < 4; n++) {
            const int row = wn + n * 16 + lr;
            bfv[n] = *(const bf16x8*)&Bc2[row * 32 + (lg ^ fread) * 8];
        }
        #pragma unroll
        for (int m = 0; m < 4; m++)
            #pragma unroll
            for (int n = 0; n < 4; n++)
                acc[m][n] = mfma16(af[m], bfv[n], acc[m][n]);

        asm volatile("s_waitcnt lgkmcnt(0)" ::: "memory");
        __builtin_amdgcn_sched_barrier(0);
        __builtin_amdgcn_s_barrier();
        cur ^= 1;
    }
    asm volatile("s_waitcnt vmcnt(0)" ::: "memory");

    #pragma unroll
    for (int n = 0; n < 4; n++) {
        const int col = tn * 128 + wn + n * 16 + lr;
        const float bv = bias[col];
        #pragma unroll
        for (int m = 0; m < 4; m++) {
            const int row0 = tm * 128 + wm + m * 16 + lg * 4;
            #pragma unroll
            for (int r = 0; r < 4; r++)
                Y[(size_t)(row0 + r) * 1024 + col] = acc[m][n][r] + bv;
        }
    }
}

// ---- flash attention: R12 version verbatim (8 waves/block, KVBLK=64, 32x32x16 MFMA,
// in-lane P, V pre-permuted in global, accl ones-column MFMA, no-max exp2 softmax,
// XOR-swizzled LDS, counted-vmcnt(2) double buffer). ----
__global__ __launch_bounds__(512, 2) void attn_fwd(
    const unsigned short* __restrict__ Q, const unsigned short* __restrict__ Kg,
    const unsigned short* __restrict__ Vtg, unsigned short* __restrict__ ctx)
{
    __shared__ short Ks[2][4096];
    __shared__ short Vs[2][4096];

    const int tid = threadIdx.x, lane = tid & 63, w = tid >> 6;   // w in 0..7
    const int l31 = lane & 31, hi = lane >> 5;

    const int blk = blockIdx.x;
    const int idx = blk >> 3;
    const int bh = (blk & 7) * 4 + (idx >> 3);
    const int qt = idx & 7;

    const unsigned short* Qb = Q   + (size_t)bh * Sc * HDc;
    const unsigned short* Kb = Kg  + (size_t)bh * Sc * HDc;
    const unsigned short* Vb = Vtg + (size_t)bh * HDc * Sc;

    const int qbase = qt * 256 + w * 32;
    bf16x8 qf[4];
    {
        const size_t qr = (size_t)(qbase + l31) * HDc + hi * 8;
        #pragma unroll
        for (int kk = 0; kk < 4; kk++)
            qf[kk] = *(const bf16x8*)&Qb[qr + kk * 16];
    }

    const int srow  = w * 8 + (lane >> 3);
    const int sslot = ((lane & 7) ^ (lane >> 3)) * 8;
    const unsigned short* Kst = Kb + (size_t)srow * HDc + sslot;
    const unsigned short* Vst = Vb + (size_t)srow * Sc + sslot;

    const int swk = lane & 7;

    const f32x16 Z = {};
    f32x16 acc0 = {}, acc1 = {}, accl = {};

    union { unsigned int u[4]; bf16x8 v; } ones;
    ones.u[0] = ones.u[1] = ones.u[2] = ones.u[3] = 0x3F803F80u;

    gload16(Kst, &Ks[0][w * 512]);
    gload16(Vst, &Vs[0][w * 512]);

    int cur = 0;
    for (int kt = 0; kt < 32; ++kt) {
        {
            const int nxt = kt < 31 ? kt + 1 : 31;
            gload16(Kst + (size_t)nxt * 4096, &Ks[cur ^ 1][w * 512]);
            gload16(Vst + nxt * 64,           &Vs[cur ^ 1][w * 512]);
        }
        asm volatile("s_waitcnt vmcnt(2)" ::: "memory");
        __builtin_amdgcn_s_barrier();
        __builtin_amdgcn_sched_barrier(0);

        const short* Kc = Ks[cur];
        const short* Vc = Vs[cur];

        f32x16 sf0, sf1;
        __builtin_amdgcn_s_setprio(1);
        {
            const int sl = (hi ^ swk) * 8;
            bf16x8 a0 = *(const bf16x8*)&Kc[l31 * 64 + sl];
            bf16x8 a1 = *(const bf16x8*)&Kc[(32 + l31) * 64 + sl];
            sf0 = mfma32(a0, qf[0], Z);
            sf1 = mfma32(a1, qf[0], Z);
        }
        #pragma unroll
        for (int kk = 1; kk < 4; kk++) {
            const int sl = ((2 * kk + hi) ^ swk) * 8;
            bf16x8 a0 = *(const bf16x8*)&Kc[l31 * 64 + sl];
            bf16x8 a1 = *(const bf16x8*)&Kc[(32 + l31) * 64 + sl];
            sf0 = mfma32(a0, qf[kk], sf0);
            sf1 = mfma32(a1, qf[kk], sf1);
        }
        __builtin_amdgcn_s_setprio(0);

        unsigned int p0[8], p1[8];
        #pragma unroll
        for (int j = 0; j < 8; j++) {
            const float a0 = __builtin_amdgcn_exp2f(sf0[2 * j]);
            const float a1 = __builtin_amdgcn_exp2f(sf0[2 * j + 1]);
            const float b0 = __builtin_amdgcn_exp2f(sf1[2 * j]);
            const float b1 = __builtin_amdgcn_exp2f(sf1[2 * j + 1]);
            asm("v_cvt_pk_bf16_f32 %0, %1, %2" : "=v"(p0[j]) : "v"(a0), "v"(a1));
            asm("v_cvt_pk_bf16_f32 %0, %1, %2" : "=v"(p1[j]) : "v"(b0), "v"(b1));
        }

        __builtin_amdgcn_s_setprio(1);
        #pragma unroll
        for (int m = 0; m < 4; m++) {
            const unsigned int* pw = (m < 2) ? &p0[(m & 1) * 4] : &p1[(m & 1) * 4];
            union { unsigned int u[4]; bf16x8 v; } af;
            af.u[0] = pw[0]; af.u[1] = pw[1]; af.u[2] = pw[2]; af.u[3] = pw[3];
            const int sl = ((2 * m + hi) ^ swk) * 8;
            bf16x8 b0 = *(const bf16x8*)&Vc[l31 * 64 + sl];
            bf16x8 b1 = *(const bf16x8*)&Vc[(32 + l31) * 64 + sl];
            acc0 = mfma32(af.v, b0, acc0);
            acc1 = mfma32(af.v, b1, acc1);
            accl = mfma32(af.v, ones.v, accl);
        }
        __builtin_amdgcn_s_setprio(0);

        asm volatile("s_waitcnt lgkmcnt(0)" ::: "memory");
        __builtin_amdgcn_sched_barrier(0);
        __builtin_amdgcn_s_barrier();
        cur ^= 1;
    }
    asm volatile("s_waitcnt vmcnt(0)" ::: "memory");

    const int b_ = bh >> 4, hh = bh & 15;
    #pragma unroll
    for (int r = 0; r < 16; r++) {
        const int qr = (r & 3) + 8 * (r >> 2) + 4 * hi;
        const float lv = __builtin_amdgcn_rcpf(accl[r]);
        const int sq = qbase + qr;
        unsigned short* co = &ctx[((size_t)(b_ * Sc + sq)) * Dc + (size_t)hh * HDc + l31];
        co[0]  = f2bf(acc0[r] * lv);
        co[32] = f2bf(acc1[r] * lv);
    }
}

extern "C" void kernel_launch(void* const* d_in, const int* in_sizes, int n_in,
                              void* d_out, int out_size, void* d_ws, size_t ws_size,
                              hipStream_t stream)
{
    const float* query = (const float*)d_in[0];
    const float* key   = (const float*)d_in[1];
    const float* value = (const float*)d_in[2];
    const float* Wq = (const float*)d_in[3];
    const float* bq = (const float*)d_in[4];
    const float* Wk = (const float*)d_in[5];
    const float* bk = (const float*)d_in[6];
    const float* Wv = (const float*)d_in[7];
    const float* bv = (const float*)d_in[8];
    const float* Wo = (const float*)d_in[9];
    const float* bo = (const float*)d_in[10];

    constexpr size_t W = 1048576, AE = 4194304;
    unsigned short* wqb = (unsigned short*)d_ws;
    unsigned short* wkb = wqb + W;
    unsigned short* wvb = wkb + W;
    unsigned short* wob = wvb + W;
    unsigned short* Qh  = wob + W;
    unsigned short* Kh  = Qh + AE;
    unsigned short* Vth = Kh + AE;
    unsigned short* cx  = Vth + AE;

    cvt_w<<<2048, 256, 0, stream>>>(Wq, Wk, Wv, Wo, wqb, wkb, wvb, wob);
    qkv_gemm<<<768, 256, 0, stream>>>(query, key, value, wqb, wkb, wvb,
                                      bq, bk, bv, Qh, Kh, Vth);
    attn_fwd<<<256, 512, 0, stream>>>(Qh, Kh, Vth, cx);
    out_gemm<<<256, 256, 0, stream>>>(cx, wob, bo, (float*)d_out);
}

// Round 16
// 107.375 us; speedup vs baseline: 1.3103x; 1.0770x over previous
//
#include <hip/hip_runtime.h>
#include <hip/hip_bf16.h>

#define DEVFN __device__ __forceinline__

typedef __attribute__((ext_vector_type(8))) short bf16x8;   // 8 bf16 = 4 VGPR
typedef __attribute__((ext_vector_type(4))) float f32x4;
typedef __attribute__((ext_vector_type(16))) float f32x16;

constexpr int Bc = 2, Sc = 2048, Dc = 1024, Hc = 16, HDc = 64;
constexpr float SCALEc = 0.125f;  // HD^-0.5
constexpr float LOG2E  = 1.44269504088896340736f;

DEVFN unsigned short f2bf(float f) {  // RNE fp32 -> bf16
    union { float f; unsigned int u; } x; x.f = f;
    return (unsigned short)((x.u + 0x7fffu + ((x.u >> 16) & 1u)) >> 16);
}

DEVFN f32x4 mfma16(bf16x8 a, bf16x8 b, f32x4 c) {
    return __builtin_amdgcn_mfma_f32_16x16x32_bf16(a, b, c, 0, 0, 0);
}
DEVFN f32x16 mfma32(bf16x8 a, bf16x8 b, f32x16 c) {
    return __builtin_amdgcn_mfma_f32_32x32x16_bf16(a, b, c, 0, 0, 0);
}

DEVFN void gload16(const void* g, void* l) {  // async global->LDS, dest = base + lane*16
    __builtin_amdgcn_global_load_lds((const __attribute__((address_space(1))) void*)g,
                                     (__attribute__((address_space(3))) void*)l, 16, 0, 0);
}

// ---- weights fp32 -> bf16 (4 x 1M elems) ----
__global__ __launch_bounds__(256) void cvt_w(
    const float* __restrict__ wq, const float* __restrict__ wk,
    const float* __restrict__ wv, const float* __restrict__ wo,
    unsigned short* __restrict__ wqb, unsigned short* __restrict__ wkb,
    unsigned short* __restrict__ wvb, unsigned short* __restrict__ wob)
{
    const unsigned t = blockIdx.x * 256 + threadIdx.x;   // 524288 threads
    const unsigned which = t >> 17, local = t & ((1u << 17) - 1);
    const float* s = which == 0 ? wq : which == 1 ? wk : which == 2 ? wv : wo;
    unsigned short* d = which == 0 ? wqb : which == 1 ? wkb : which == 2 ? wvb : wob;
    const size_t off = (size_t)local * 8;
    float4 v0 = *(const float4*)(s + off);
    float4 v1 = *(const float4*)(s + off + 4);
    unsigned short t8[8] = {f2bf(v0.x), f2bf(v0.y), f2bf(v0.z), f2bf(v0.w),
                            f2bf(v1.x), f2bf(v1.y), f2bf(v1.z), f2bf(v1.w)};
    *(uint4*)(d + off) = *(const uint4*)t8;
}

// ---- fused QKV projection: R15 structure but 3-buffer rotation with ONE barrier per
// K-step (writer at step k touches buf (k+1)%3; slowest co-resident wave reads buf
// (k-1)%3 -> gap 2 mod 3, race-free). vmcnt(10) = B(k+1)2 + A(k+2)4 + A(k+1)4 newer
// than B(k). XCD-aware block grouping. Q pre-scaled by SCALE*log2e.
// g<2: out [B,H,S,HD]; g==2: out [B,H,HD,S], k-bits 2<->3 swapped per 16-group.
__global__ __launch_bounds__(256, 3) void qkv_gemm(
    const float* __restrict__ Aq, const float* __restrict__ Ak, const float* __restrict__ Av,
    const unsigned short* __restrict__ Wqb, const unsigned short* __restrict__ Wkb,
    const unsigned short* __restrict__ Wvb,
    const float* __restrict__ bqp, const float* __restrict__ bkp, const float* __restrict__ bvp,
    unsigned short* __restrict__ Qo, unsigned short* __restrict__ Ko, unsigned short* __restrict__ Vto)
{
    __shared__ short As[3 * 4096];
    __shared__ short Bs[3 * 4096];

    // XCD-aware decode: lgid ordered g*256 + tm*8 + tn; XCD x gets lgids [96x, 96x+96)
    const int lgid = (blockIdx.x & 7) * 96 + (blockIdx.x >> 3);
    const int g = lgid >> 8;
    const int rem = lgid & 255;
    const int tm = rem >> 3, tn = rem & 7;

    const float* A = g == 0 ? Aq : g == 1 ? Ak : Av;
    const unsigned short* Bw = g == 0 ? Wqb : g == 1 ? Wkb : Wvb;
    const float* bias = g == 0 ? bqp : g == 1 ? bkp : bvp;
    const float scale = g == 0 ? SCALEc * LOG2E : 1.0f;

    const int tid = threadIdx.x, lane = tid & 63, w = tid >> 6;
    const int lr = lane & 15, lg = lane >> 4;
    const int wm = (w >> 1) * 64, wn = (w & 1) * 64;

    // chunk c: lane -> row c*16+(l>>2), swizzled 8-elem slot (l&3)^((row>>1)&3)
    const int c0 = 2 * w, c1 = 2 * w + 1;
    const int r0 = c0 * 16 + (lane >> 2), r1 = c1 * 16 + (lane >> 2);
    const int s0 = (lane & 3) ^ ((r0 >> 1) & 3), s1 = (lane & 3) ^ ((r1 >> 1) & 3);
    const float* Afp0 = A + (size_t)(tm * 128 + r0) * 1024 + s0 * 8;
    const float* Afp1 = A + (size_t)(tm * 128 + r1) * 1024 + s1 * 8;
    const unsigned short* Bp0 = Bw + (size_t)(tn * 128 + r0) * 1024 + s0 * 8;
    const unsigned short* Bp1 = Bw + (size_t)(tn * 128 + r1) * 1024 + s1 * 8;
    const int aw0 = c0 * 512 + lane * 8;   // linear LDS write slots (source swizzled)
    const int aw1 = c1 * 512 + lane * 8;

    f32x4 acc[4][4] = {};
    const int fread = (lr >> 1) & 3;

    float4 fE[4], fO[4];   // A reg tiles: even steps in fE, odd in fO (static idx only)

#define CVT_A(R, WOFS)                                                           \
    {                                                                            \
        unsigned int q0, q1, q2, q3;                                             \
        asm("v_cvt_pk_bf16_f32 %0,%1,%2" : "=v"(q0) : "v"(R[0].x), "v"(R[0].y)); \
        asm("v_cvt_pk_bf16_f32 %0,%1,%2" : "=v"(q1) : "v"(R[0].z), "v"(R[0].w)); \
        asm("v_cvt_pk_bf16_f32 %0,%1,%2" : "=v"(q2) : "v"(R[1].x), "v"(R[1].y)); \
        asm("v_cvt_pk_bf16_f32 %0,%1,%2" : "=v"(q3) : "v"(R[1].z), "v"(R[1].w)); \
        *(uint4*)&As[(WOFS) + aw0] = (uint4){q0, q1, q2, q3};                    \
        asm("v_cvt_pk_bf16_f32 %0,%1,%2" : "=v"(q0) : "v"(R[2].x), "v"(R[2].y)); \
        asm("v_cvt_pk_bf16_f32 %0,%1,%2" : "=v"(q1) : "v"(R[2].z), "v"(R[2].w)); \
        asm("v_cvt_pk_bf16_f32 %0,%1,%2" : "=v"(q2) : "v"(R[3].x), "v"(R[3].y)); \
        asm("v_cvt_pk_bf16_f32 %0,%1,%2" : "=v"(q3) : "v"(R[3].z), "v"(R[3].w)); \
        *(uint4*)&As[(WOFS) + aw1] = (uint4){q0, q1, q2, q3};                    \
    }

    // ---- prologue: B(0)->Bs[0]; A(0)->fE->As[0]; A(1)->fO ----
    gload16(Bp0, &Bs[c0 * 512]);
    gload16(Bp1, &Bs[c1 * 512]);
    fE[0] = *(const float4*)(Afp0);     fE[1] = *(const float4*)(Afp0 + 4);
    fE[2] = *(const float4*)(Afp1);     fE[3] = *(const float4*)(Afp1 + 4);
    CVT_A(fE, 0)
    fO[0] = *(const float4*)(Afp0 + 32); fO[1] = *(const float4*)(Afp0 + 36);
    fO[2] = *(const float4*)(Afp1 + 32); fO[3] = *(const float4*)(Afp1 + 36);
    asm volatile("s_waitcnt lgkmcnt(0)" ::: "memory");   // As[0] writes drained

    // per step KT: issue B(KT+1)->Bs[wb], A(KT+2)->FI; vmcnt(10); ONE barrier;
    // MFMA on buf rb; cvt FC (=A(KT+1)) -> As[wb]; lgkm drain; (next iter's barrier).
#define QKV_STEP(KT, RB, WOFS, FI, FC)                                           \
    {                                                                            \
        const int k1 = ((KT) < 31) ? ((KT) + 1) * 32 : 992;                      \
        const int k2 = ((KT) < 30) ? ((KT) + 2) * 32 : 992;                      \
        gload16(Bp0 + k1, &Bs[(WOFS) + c0 * 512]);                               \
        gload16(Bp1 + k1, &Bs[(WOFS) + c1 * 512]);                               \
        FI[0] = *(const float4*)(Afp0 + k2); FI[1] = *(const float4*)(Afp0 + k2 + 4); \
        FI[2] = *(const float4*)(Afp1 + k2); FI[3] = *(const float4*)(Afp1 + k2 + 4); \
        asm volatile("s_waitcnt vmcnt(10)" ::: "memory");                        \
        __builtin_amdgcn_s_barrier();                                            \
        __builtin_amdgcn_sched_barrier(0);                                       \
        const short* Ac  = &As[RB];                                              \
        const short* Bc2 = &Bs[RB];                                              \
        bf16x8 af[4], bfv[4];                                                    \
        _Pragma("unroll")                                                        \
        for (int m = 0; m < 4; m++) {                                            \
            const int row = wm + m * 16 + lr;                                    \
            af[m] = *(const bf16x8*)&Ac[row * 32 + (lg ^ fread) * 8];            \
        }                                                                        \
        _Pragma("unroll")                                                        \
        for (int n = 0; n < 4; n++) {                                            \
            const int row = wn + n * 16 + lr;                                    \
            bfv[n] = *(const bf16x8*)&Bc2[row * 32 + (lg ^ fread) * 8];          \
        }                                                                        \
        _Pragma("unroll")                                                        \
        for (int m = 0; m < 4; m++)                                              \
            _Pragma("unroll")                                                    \
            for (int n = 0; n < 4; n++)                                          \
                acc[m][n] = mfma16(af[m], bfv[n], acc[m][n]);                    \
        CVT_A(FC, WOFS)                                                          \
        asm volatile("s_waitcnt lgkmcnt(0)" ::: "memory");                       \
        __builtin_amdgcn_sched_barrier(0);                                       \
    }

    int rb = 0;   // read-buffer byte/short offset rotates 0 -> 4096 -> 8192 -> 0
    for (int kt = 0; kt < 32; kt += 2) {
        const int wb0 = rb == 8192 ? 0 : rb + 4096;
        QKV_STEP(kt, rb, wb0, fE, fO)
        const int wb1 = wb0 == 8192 ? 0 : wb0 + 4096;
        QKV_STEP(kt + 1, wb0, wb1, fO, fE)
        rb = wb1;
    }
    asm volatile("s_waitcnt vmcnt(0)" ::: "memory");   // drain clamped dup stages
#undef QKV_STEP
#undef CVT_A

    if (g < 2) {
        unsigned short* Y = g == 0 ? Qo : Ko;
        #pragma unroll
        for (int n = 0; n < 4; n++) {
            const int col = tn * 128 + wn + n * 16 + lr;
            const float bv = bias[col];
            const int hh = col >> 6, hd = col & 63;
            #pragma unroll
            for (int m = 0; m < 4; m++) {
                const int row0 = tm * 128 + wm + m * 16 + lg * 4;
                const int b_ = row0 >> 11, sQ = row0 & 2047;
                #pragma unroll
                for (int r = 0; r < 4; r++) {
                    const float val = (acc[m][n][r] + bv) * scale;
                    Y[(((size_t)(b_ * Hc + hh)) * Sc + (sQ + r)) * HDc + hd] = f2bf(val);
                }
            }
        }
    } else {
        #pragma unroll
        for (int n = 0; n < 4; n++) {
            const int col = tn * 128 + wn + n * 16 + lr;
            const float bv = bias[col];
            const int hh = col >> 6, hd = col & 63;
            #pragma unroll
            for (int m = 0; m < 4; m++) {
                const int row0 = tm * 128 + wm + m * 16 + lg * 4;
                const int b_ = row0 >> 11, sQ = row0 & 2047;
                const int sQp = (sQ & ~12) | ((sQ & 4) << 1) | ((sQ & 8) >> 1);  // k bits 2<->3
                unsigned long long pk = 0;
                #pragma unroll
                for (int r = 0; r < 4; r++)
                    pk |= (unsigned long long)f2bf(acc[m][n][r] + bv) << (16 * r);
                *(unsigned long long*)&Vto[(((size_t)(b_ * Hc + hh)) * HDc + hd) * Sc + sQp] = pk;
            }
        }
    }
}

// ---- output projection: 3-buffer single-barrier version (pure bf16, XCD-grouped) ----
__global__ __launch_bounds__(256) void out_gemm(
    const unsigned short* __restrict__ Ab, const unsigned short* __restrict__ Bw,
    const float* __restrict__ bias, float* __restrict__ Y)
{
    __shared__ short As[3 * 4096];
    __shared__ short Bs[3 * 4096];
    const int tid = threadIdx.x, lane = tid & 63, w = tid >> 6;
    const int lr = lane & 15, lg = lane >> 4;
    const int lgid = (blockIdx.x & 7) * 32 + (blockIdx.x >> 3);
    const int tm = lgid >> 3, tn = lgid & 7;
    const int wm = (w >> 1) * 64, wn = (w & 1) * 64;

    const int c0 = 2 * w, c1 = 2 * w + 1;
    const int r0 = c0 * 16 + (lane >> 2), r1 = c1 * 16 + (lane >> 2);
    const int sl0 = ((lane & 3) ^ ((r0 >> 1) & 3)) * 8, sl1 = ((lane & 3) ^ ((r1 >> 1) & 3)) * 8;
    const unsigned short* Ap0 = Ab + (size_t)(tm * 128 + r0) * 1024 + sl0;
    const unsigned short* Ap1 = Ab + (size_t)(tm * 128 + r1) * 1024 + sl1;
    const unsigned short* Bp0 = Bw + (size_t)(tn * 128 + r0) * 1024 + sl0;
    const unsigned short* Bp1 = Bw + (size_t)(tn * 128 + r1) * 1024 + sl1;

    f32x4 acc[4][4] = {};
    const int fread = (lr >> 1) & 3;

    // prologue: tiles 0,1 into bufs 0,1 (depth-1 rotation thereafter)
    gload16(Ap0,      &As[c0 * 512]);
    gload16(Ap1,      &As[c1 * 512]);
    gload16(Bp0,      &Bs[c0 * 512]);
    gload16(Bp1,      &Bs[c1 * 512]);

    int rb = 0;
    for (int k0 = 0; k0 < 1024; k0 += 32) {
        const int wb = rb == 8192 ? 0 : rb + 4096;
        const int nk = (k0 + 32 < 1024) ? k0 + 32 : k0;
        gload16(Ap0 + nk, &As[wb + c0 * 512]);
        gload16(Ap1 + nk, &As[wb + c1 * 512]);
        gload16(Bp0 + nk, &Bs[wb + c0 * 512]);
        gload16(Bp1 + nk, &Bs[wb + c1 * 512]);
        asm volatile("s_waitcnt vmcnt(4)" ::: "memory");   // tile k0's 4 done
        __builtin_amdgcn_s_barrier();
        __builtin_amdgcn_sched_barrier(0);

        const short* Ac  = &As[rb];
        const short* Bc2 = &Bs[rb];
        bf16x8 af[4], bfv[4];
        #pragma unroll
        for (int m = 0; m < 4; m++) {
            const int row = wm + m * 16 + lr;
            af[m] = *(const bf16x8*)&Ac[row * 32 + (lg ^ fread) * 8];
        }
        #pragma unroll
        for (int n = 0; n < 4; n++) {
            const int row = wn + n * 16 + lr;
            bfv[n] = *(const bf16x8*)&Bc2[row * 32 + (lg ^ fread) * 8];
        }
        #pragma unroll
        for (int m = 0; m < 4; m++)
            #pragma unroll
            for (int n = 0; n < 4; n++)
                acc[m][n] = mfma16(af[m], bfv[n], acc[m][n]);
        rb = wb;
    }
    asm volatile("s_waitcnt vmcnt(0)" ::: "memory");

    #pragma unroll
    for (int n = 0; n < 4; n++) {
        const int col = tn * 128 + wn + n * 16 + lr;
        const float bv = bias[col];
        #pragma unroll
        for (int m = 0; m < 4; m++) {
            const int row0 = tm * 128 + wm + m * 16 + lg * 4;
            #pragma unroll
            for (int r = 0; r < 4; r++)
                Y[(size_t)(row0 + r) * 1024 + col] = acc[m][n][r] + bv;
        }
    }
}

// ---- flash attention: R15 per-iter math, 4-buffer depth-2 rotation, ONE barrier/iter
// (writer at iter k touches buf (k+2)&3; slowest wave reads buf (k-1)&3 -> gap 3 mod 4).
// vmcnt(4) = 2 in-flight tiles x 2 loads newer than tile k.
__global__ __launch_bounds__(512, 2) void attn_fwd(
    const unsigned short* __restrict__ Q, const unsigned short* __restrict__ Kg,
    const unsigned short* __restrict__ Vtg, unsigned short* __restrict__ ctx)
{
    __shared__ short Ks[4][4096];
    __shared__ short Vs[4][4096];

    const int tid = threadIdx.x, lane = tid & 63, w = tid >> 6;   // w in 0..7
    const int l31 = lane & 31, hi = lane >> 5;

    const int blk = blockIdx.x;
    const int idx = blk >> 3;
    const int bh = (blk & 7) * 4 + (idx >> 3);
    const int qt = idx & 7;

    const unsigned short* Qb = Q   + (size_t)bh * Sc * HDc;
    const unsigned short* Kb = Kg  + (size_t)bh * Sc * HDc;
    const unsigned short* Vb = Vtg + (size_t)bh * HDc * Sc;

    const int qbase = qt * 256 + w * 32;
    bf16x8 qf[4];
    {
        const size_t qr = (size_t)(qbase + l31) * HDc + hi * 8;
        #pragma unroll
        for (int kk = 0; kk < 4; kk++)
            qf[kk] = *(const bf16x8*)&Qb[qr + kk * 16];
    }

    const int srow  = w * 8 + (lane >> 3);
    const int sslot = ((lane & 7) ^ (lane >> 3)) * 8;
    const unsigned short* Kst = Kb + (size_t)srow * HDc + sslot;
    const unsigned short* Vst = Vb + (size_t)srow * Sc + sslot;

    const int swk = lane & 7;

    const f32x16 Z = {};
    f32x16 acc0 = {}, acc1 = {}, accl = {};

    union { unsigned int u[4]; bf16x8 v; } ones;
    ones.u[0] = ones.u[1] = ones.u[2] = ones.u[3] = 0x3F803F80u;

    // prologue: tiles 0,1 into bufs 0,1 (4 loads in flight)
    gload16(Kst,        &Ks[0][w * 512]);
    gload16(Vst,        &Vs[0][w * 512]);
    gload16(Kst + 4096, &Ks[1][w * 512]);
    gload16(Vst + 64,   &Vs[1][w * 512]);

    for (int kt = 0; kt < 32; ++kt) {
        {   // stage tile kt+2 (clamped dup on last iters keeps vmcnt uniform)
            const int nxt = kt < 30 ? kt + 2 : 31;
            const int wb = (kt + 2) & 3;
            gload16(Kst + (size_t)nxt * 4096, &Ks[wb][w * 512]);
            gload16(Vst + nxt * 64,           &Vs[wb][w * 512]);
        }
        asm volatile("s_waitcnt vmcnt(4)" ::: "memory");   // tile kt's 2 done
        __builtin_amdgcn_s_barrier();
        __builtin_amdgcn_sched_barrier(0);

        const short* Kc = Ks[kt & 3];
        const short* Vc = Vs[kt & 3];

        f32x16 sf0, sf1;
        __builtin_amdgcn_s_setprio(1);
        {
            const int sl = (hi ^ swk) * 8;
            bf16x8 a0 = *(const bf16x8*)&Kc[l31 * 64 + sl];
            bf16x8 a1 = *(const bf16x8*)&Kc[(32 + l31) * 64 + sl];
            sf0 = mfma32(a0, qf[0], Z);
            sf1 = mfma32(a1, qf[0], Z);
        }
        #pragma unroll
        for (int kk = 1; kk < 4; kk++) {
            const int sl = ((2 * kk + hi) ^ swk) * 8;
            bf16x8 a0 = *(const bf16x8*)&Kc[l31 * 64 + sl];
            bf16x8 a1 = *(const bf16x8*)&Kc[(32 + l31) * 64 + sl];
            sf0 = mfma32(a0, qf[kk], sf0);
            sf1 = mfma32(a1, qf[kk], sf1);
        }
        __builtin_amdgcn_s_setprio(0);

        unsigned int p0[8], p1[8];
        #pragma unroll
        for (int j = 0; j < 8; j++) {
            const float a0 = __builtin_amdgcn_exp2f(sf0[2 * j]);
            const float a1 = __builtin_amdgcn_exp2f(sf0[2 * j + 1]);
            const float b0 = __builtin_amdgcn_exp2f(sf1[2 * j]);
            const float b1 = __builtin_amdgcn_exp2f(sf1[2 * j + 1]);
            asm("v_cvt_pk_bf16_f32 %0, %1, %2" : "=v"(p0[j]) : "v"(a0), "v"(a1));
            asm("v_cvt_pk_bf16_f32 %0, %1, %2" : "=v"(p1[j]) : "v"(b0), "v"(b1));
        }

        __builtin_amdgcn_s_setprio(1);
        #pragma unroll
        for (int m = 0; m < 4; m++) {
            const unsigned int* pw = (m < 2) ? &p0[(m & 1) * 4] : &p1[(m & 1) * 4];
            union { unsigned int u[4]; bf16x8 v; } af;
            af.u[0] = pw[0]; af.u[1] = pw[1]; af.u[2] = pw[2]; af.u[3] = pw[3];
            const int sl = ((2 * m + hi) ^ swk) * 8;
            bf16x8 b0 = *(const bf16x8*)&Vc[l31 * 64 + sl];
            bf16x8 b1 = *(const bf16x8*)&Vc[(32 + l31) * 64 + sl];
            acc0 = mfma32(af.v, b0, acc0);
            acc1 = mfma32(af.v, b1, acc1);
            accl = mfma32(af.v, ones.v, accl);
        }
        __builtin_amdgcn_s_setprio(0);
        // no trailing barrier: ds_reads are consumed before the wave reaches the
        // next iteration's barrier; 4-buffer rotation keeps writes 3 bufs away.
    }
    asm volatile("s_waitcnt vmcnt(0)" ::: "memory");

    const int b_ = bh >> 4, hh = bh & 15;
    #pragma unroll
    for (int r = 0; r < 16; r++) {
        const int qr = (r & 3) + 8 * (r >> 2) + 4 * hi;
        const float lv = __builtin_amdgcn_rcpf(accl[r]);
        const int sq = qbase + qr;
        unsigned short* co = &ctx[((size_t)(b_ * Sc + sq)) * Dc + (size_t)hh * HDc + l31];
        co[0]  = f2bf(acc0[r] * lv);
        co[32] = f2bf(acc1[r] * lv);
    }
}

extern "C" void kernel_launch(void* const* d_in, const int* in_sizes, int n_in,
                              void* d_out, int out_size, void* d_ws, size_t ws_size,
                              hipStream_t stream)
{
    const float* query = (const float*)d_in[0];
    const float* key   = (const float*)d_in[1];
    const float* value = (const float*)d_in[2];
    const float* Wq = (const float*)d_in[3];
    const float* bq = (const float*)d_in[4];
    const float* Wk = (const float*)d_in[5];
    const float* bk = (const float*)d_in[6];
    const float* Wv = (const float*)d_in[7];
    const float* bv = (const float*)d_in[8];
    const float* Wo = (const float*)d_in[9];
    const float* bo = (const float*)d_in[10];

    constexpr size_t W = 1048576, AE = 4194304;
    unsigned short* wqb = (unsigned short*)d_ws;
    unsigned short* wkb = wqb + W;
    unsigned short* wvb = wkb + W;
    unsigned short* wob = wvb + W;
    unsigned short* Qh  = wob + W;
    unsigned short* Kh  = Qh + AE;
    unsigned short* Vth = Kh + AE;
    unsigned short* cx  = Vth + AE;

    cvt_w<<<2048, 256, 0, stream>>>(Wq, Wk, Wv, Wo, wqb, wkb, wvb, wob);
    qkv_gemm<<<768, 256, 0, stream>>>(query, key, value, wqb, wkb, wvb,
                                      bq, bk, bv, Qh, Kh, Vth);
    attn_fwd<<<256, 512, 0, stream>>>(Qh, Kh, Vth, cx);
    out_gemm<<<256, 256, 0, stream>>>(cx, wob, bo, (float*)d_out);
}